// Round 2
// baseline (2725.874 us; speedup 1.0000x reference)
//
#include <hip/hip_runtime.h>
#include <hip/hip_bf16.h>

#define NN 50000
#define NE 500000
#define DD 128
#define HCC 128
#define TDD 32
#define MDD 64
#define KEE 96

// ---------------------------------------------------------------------------
// K1: node projections q/k/v/skip = x @ W + b  (all f32), zero numer/denom.
// Block = 256 thr (4 waves), 64 nodes per block. Wave handles 16 nodes.
// Lane owns 2 output columns (c = 2*lane, 2*lane+1) of each of the 4 matrices.
// ---------------------------------------------------------------------------
__global__ __launch_bounds__(256) void node_proj_kernel(
    const float* __restrict__ x,
    const float* __restrict__ Wq, const float* __restrict__ bq,
    const float* __restrict__ Wk, const float* __restrict__ bk,
    const float* __restrict__ Wv, const float* __restrict__ bv,
    const float* __restrict__ Wsk, const float* __restrict__ bsk,
    float* __restrict__ qn, float* __restrict__ kn, float* __restrict__ vn,
    float* __restrict__ skipn, float* __restrict__ numer, float* __restrict__ denom)
{
    __shared__ float xs[64 * DD];  // 32 KB
    const int node0 = blockIdx.x * 64;
    for (int i = threadIdx.x; i < 64 * DD; i += 256) {
        int node = node0 + (i >> 7);
        xs[i] = (node < NN) ? x[(size_t)node * DD + (i & 127)] : 0.f;
    }
    __syncthreads();

    const int wave = threadIdx.x >> 6;
    const int lane = threadIdx.x & 63;
    const int nb = wave * 16;  // first node (within block) this wave owns

    float a0[16][2], a1[16][2], a2[16][2], a3[16][2];
    #pragma unroll
    for (int n = 0; n < 16; n++) {
        a0[n][0]=0.f; a0[n][1]=0.f; a1[n][0]=0.f; a1[n][1]=0.f;
        a2[n][0]=0.f; a2[n][1]=0.f; a3[n][0]=0.f; a3[n][1]=0.f;
    }

    const float2* W2q = (const float2*)Wq;
    const float2* W2k = (const float2*)Wk;
    const float2* W2v = (const float2*)Wv;
    const float2* W2s = (const float2*)Wsk;

    for (int k = 0; k < DD; k++) {
        float2 wq = W2q[k * 64 + lane];
        float2 wk = W2k[k * 64 + lane];
        float2 wv = W2v[k * 64 + lane];
        float2 ws = W2s[k * 64 + lane];
        const float* xcol = &xs[nb * DD + k];
        #pragma unroll
        for (int n = 0; n < 16; n++) {
            float xb = xcol[n * DD];  // LDS broadcast
            a0[n][0] = fmaf(xb, wq.x, a0[n][0]); a0[n][1] = fmaf(xb, wq.y, a0[n][1]);
            a1[n][0] = fmaf(xb, wk.x, a1[n][0]); a1[n][1] = fmaf(xb, wk.y, a1[n][1]);
            a2[n][0] = fmaf(xb, wv.x, a2[n][0]); a2[n][1] = fmaf(xb, wv.y, a2[n][1]);
            a3[n][0] = fmaf(xb, ws.x, a3[n][0]); a3[n][1] = fmaf(xb, ws.y, a3[n][1]);
        }
    }

    float2 bbq = ((const float2*)bq)[lane];
    float2 bbk = ((const float2*)bk)[lane];
    float2 bbv = ((const float2*)bv)[lane];
    float2 bbs = ((const float2*)bsk)[lane];

    #pragma unroll 1
    for (int n = 0; n < 16; n++) {
        int node = node0 + nb + n;
        if (node >= NN) break;
        size_t base = (size_t)node * HCC + lane * 2;
        float2 v;
        v.x = a0[n][0] + bbq.x; v.y = a0[n][1] + bbq.y; *(float2*)&qn[base]    = v;
        v.x = a1[n][0] + bbk.x; v.y = a1[n][1] + bbk.y; *(float2*)&kn[base]    = v;
        v.x = a2[n][0] + bbv.x; v.y = a2[n][1] + bbv.y; *(float2*)&vn[base]    = v;
        v.x = a3[n][0] + bbs.x; v.y = a3[n][1] + bbs.y; *(float2*)&skipn[base] = v;
        v.x = 0.f; v.y = 0.f;                           *(float2*)&numer[base] = v;
        if (lane < 2) denom[node * 2 + lane] = 0.f;
    }
}

// ---------------------------------------------------------------------------
// K2: one wave per edge. We (96x128 f32 = 48 KB) staged in LDS. edge_attr in
// regs (lane j holds attr[j]; lanes 0..31 also attr[64+j]); broadcast via
// constant-lane __shfl (lowers to v_readlane).
// Single pass: accumulate un-normalized softmax numerator + denominator.
// Valid because |alpha| is small (std ~0.4, max ~5) -> no exp overflow.
// ---------------------------------------------------------------------------
__global__ __launch_bounds__(256) void edge_kernel(
    const int* __restrict__ ei, const int* __restrict__ et,
    const float* __restrict__ msg,
    const float* __restrict__ Wt, const float* __restrict__ bt,
    const float* __restrict__ We,
    const float* __restrict__ qn, const float* __restrict__ kn,
    const float* __restrict__ vn,
    float* __restrict__ numer, float* __restrict__ denom)
{
    __shared__ float2 we_s[KEE * 64];   // 96 x 128 f32 = 48 KB; row j at we_s[j*64]
    __shared__ float wt_s[TDD], bt_s[TDD];
    const float2* We2 = (const float2*)We;
    for (int i = threadIdx.x; i < KEE * 64; i += 256) we_s[i] = We2[i];
    if (threadIdx.x < TDD) {
        wt_s[threadIdx.x] = Wt[threadIdx.x];
        bt_s[threadIdx.x] = bt[threadIdx.x];
    }
    __syncthreads();

    const int lane = threadIdx.x & 63;
    const int gw = (blockIdx.x * 256 + threadIdx.x) >> 6;
    const int nw = (gridDim.x * 256) >> 6;
    const int c0 = lane * 2;

    for (int e = gw; e < NE; e += nw) {
        int src = ei[e];
        int dst = ei[NE + e];
        float t = (float)et[e];

        // edge_attr: attr[0..31] = cos time-enc, attr[32..95] = msg.
        // lane j holds attr[j] in r0; lanes 0..31 hold attr[64+j] in r1.
        float r0, r1 = 0.f;
        if (lane < TDD) {
            r0 = cosf(t * wt_s[lane] + bt_s[lane]);
            r1 = msg[(size_t)e * MDD + 32 + lane];
        } else {
            r0 = msg[(size_t)e * MDD + (lane - 32)];
        }

        // e_vec for this lane's two columns
        float ev0 = 0.f, ev1 = 0.f;
        #pragma unroll
        for (int j = 0; j < 64; j++) {
            float aj = __shfl(r0, j, 64);                 // constant lane -> readlane
            float2 w = we_s[j * 64 + lane];
            ev0 = fmaf(aj, w.x, ev0);
            ev1 = fmaf(aj, w.y, ev1);
        }
        #pragma unroll
        for (int j = 0; j < 32; j++) {
            float aj = __shfl(r1, j, 64);
            float2 w = we_s[(64 + j) * 64 + lane];
            ev0 = fmaf(aj, w.x, ev0);
            ev1 = fmaf(aj, w.y, ev1);
        }

        float2 q2 = *(const float2*)&qn[(size_t)dst * HCC + c0];
        float2 k2 = *(const float2*)&kn[(size_t)src * HCC + c0];
        float2 v2 = *(const float2*)&vn[(size_t)src * HCC + c0];

        // per-head dot: lanes 0..31 hold head 0 cols, lanes 32..63 head 1
        float p = q2.x * (k2.x + ev0) + q2.y * (k2.y + ev1);
        #pragma unroll
        for (int m = 1; m < 32; m <<= 1) p += __shfl_xor(p, m, 64);
        float ex = expf(p * 0.125f);  // / sqrt(C=64)

        if (lane == 0)  unsafeAtomicAdd(&denom[dst * 2 + 0], ex);
        if (lane == 32) unsafeAtomicAdd(&denom[dst * 2 + 1], ex);
        unsafeAtomicAdd(&numer[(size_t)dst * HCC + c0],     ex * (v2.x + ev0));
        unsafeAtomicAdd(&numer[(size_t)dst * HCC + c0 + 1], ex * (v2.y + ev1));
    }
}

// ---------------------------------------------------------------------------
// K3: out = numer / (denom + 1e-16) + skip (f32 out). One float2 / thread.
// ---------------------------------------------------------------------------
__global__ __launch_bounds__(256) void finalize_kernel(
    const float* __restrict__ numer, const float* __restrict__ denom,
    const float* __restrict__ skipn, float* __restrict__ out)
{
    int i = blockIdx.x * 256 + threadIdx.x;  // float2-pair index
    if (i >= NN * 64) return;
    int node = i >> 6;
    int h = (i & 63) >> 5;
    float2 nu = *(const float2*)&numer[(size_t)i * 2];
    float2 sk = *(const float2*)&skipn[(size_t)i * 2];
    float dn = denom[node * 2 + h] + 1e-16f;
    float2 v;
    v.x = nu.x / dn + sk.x;
    v.y = nu.y / dn + sk.y;
    ((float2*)out)[i] = v;
}

extern "C" void kernel_launch(void* const* d_in, const int* in_sizes, int n_in,
                              void* d_out, int out_size, void* d_ws, size_t ws_size,
                              hipStream_t stream) {
    const float* x   = (const float*)d_in[0];
    const int* ei    = (const int*)d_in[1];
    const int* et    = (const int*)d_in[2];
    const float* msg = (const float*)d_in[3];
    const float* Wt  = (const float*)d_in[4];
    const float* bt  = (const float*)d_in[5];
    const float* Wq  = (const float*)d_in[6];
    const float* bq  = (const float*)d_in[7];
    const float* Wk  = (const float*)d_in[8];
    const float* bk  = (const float*)d_in[9];
    const float* Wv  = (const float*)d_in[10];
    const float* bv  = (const float*)d_in[11];
    const float* We  = (const float*)d_in[12];
    const float* Wsk = (const float*)d_in[13];
    const float* bsk = (const float*)d_in[14];

    const size_t nf = (size_t)NN * HCC;
    float* qn    = (float*)d_ws;
    float* kn    = qn + nf;
    float* vn    = kn + nf;
    float* skipn = vn + nf;
    float* numer = skipn + nf;
    float* denom = numer + nf;
    size_t need = (5 * nf + (size_t)NN * 2) * sizeof(float);
    if (ws_size < need) return;  // visible failure rather than corruption

    node_proj_kernel<<<(NN + 63) / 64, 256, 0, stream>>>(
        x, Wq, bq, Wk, bk, Wv, bv, Wsk, bsk, qn, kn, vn, skipn, numer, denom);
    edge_kernel<<<1024, 256, 0, stream>>>(
        ei, et, msg, Wt, bt, We, qn, kn, vn, numer, denom);
    finalize_kernel<<<(NN * 64 + 255) / 256, 256, 0, stream>>>(
        numer, denom, skipn, (float*)d_out);
}

// Round 3
// 1679.826 us; speedup vs baseline: 1.6227x; 1.6227x over previous
//
#include <hip/hip_runtime.h>
#include <hip/hip_bf16.h>

#define NN 50000
#define NE 500000
#define DD 128
#define HCC 128
#define TDD 32
#define MDD 64

typedef __hip_bfloat16 bf16;

// ---------------------------------------------------------------------------
// K1: node projections q/k/v/skip = x @ W + b (f32). Also zeroes cnt[].
// Block = 256 thr, 64 nodes per block; wave handles 16 nodes; lane owns 2 cols.
// ---------------------------------------------------------------------------
__global__ __launch_bounds__(256) void node_proj_kernel(
    const float* __restrict__ x,
    const float* __restrict__ Wq, const float* __restrict__ bq,
    const float* __restrict__ Wk, const float* __restrict__ bk,
    const float* __restrict__ Wv, const float* __restrict__ bv,
    const float* __restrict__ Wsk, const float* __restrict__ bsk,
    float* __restrict__ qn, float* __restrict__ kn, float* __restrict__ vn,
    float* __restrict__ skipn, int* __restrict__ cnt)
{
    int gid = blockIdx.x * 256 + threadIdx.x;
    if (gid < NN) cnt[gid] = 0;

    __shared__ float xs[64 * DD];  // 32 KB
    const int node0 = blockIdx.x * 64;
    for (int i = threadIdx.x; i < 64 * DD; i += 256) {
        int node = node0 + (i >> 7);
        xs[i] = (node < NN) ? x[(size_t)node * DD + (i & 127)] : 0.f;
    }
    __syncthreads();

    const int wave = threadIdx.x >> 6;
    const int lane = threadIdx.x & 63;
    const int nb = wave * 16;

    float a0[16][2], a1[16][2], a2[16][2], a3[16][2];
    #pragma unroll
    for (int n = 0; n < 16; n++) {
        a0[n][0]=0.f; a0[n][1]=0.f; a1[n][0]=0.f; a1[n][1]=0.f;
        a2[n][0]=0.f; a2[n][1]=0.f; a3[n][0]=0.f; a3[n][1]=0.f;
    }

    const float2* W2q = (const float2*)Wq;
    const float2* W2k = (const float2*)Wk;
    const float2* W2v = (const float2*)Wv;
    const float2* W2s = (const float2*)Wsk;

    for (int k = 0; k < DD; k++) {
        float2 wq = W2q[k * 64 + lane];
        float2 wk = W2k[k * 64 + lane];
        float2 wv = W2v[k * 64 + lane];
        float2 ws = W2s[k * 64 + lane];
        const float* xcol = &xs[nb * DD + k];
        #pragma unroll
        for (int n = 0; n < 16; n++) {
            float xb = xcol[n * DD];
            a0[n][0] = fmaf(xb, wq.x, a0[n][0]); a0[n][1] = fmaf(xb, wq.y, a0[n][1]);
            a1[n][0] = fmaf(xb, wk.x, a1[n][0]); a1[n][1] = fmaf(xb, wk.y, a1[n][1]);
            a2[n][0] = fmaf(xb, wv.x, a2[n][0]); a2[n][1] = fmaf(xb, wv.y, a2[n][1]);
            a3[n][0] = fmaf(xb, ws.x, a3[n][0]); a3[n][1] = fmaf(xb, ws.y, a3[n][1]);
        }
    }

    float2 bbq = ((const float2*)bq)[lane];
    float2 bbk = ((const float2*)bk)[lane];
    float2 bbv = ((const float2*)bv)[lane];
    float2 bbs = ((const float2*)bsk)[lane];

    #pragma unroll 1
    for (int n = 0; n < 16; n++) {
        int node = node0 + nb + n;
        if (node >= NN) break;
        size_t base = (size_t)node * HCC + lane * 2;
        float2 v;
        v.x = a0[n][0] + bbq.x; v.y = a0[n][1] + bbq.y; *(float2*)&qn[base]    = v;
        v.x = a1[n][0] + bbk.x; v.y = a1[n][1] + bbk.y; *(float2*)&kn[base]    = v;
        v.x = a2[n][0] + bbv.x; v.y = a2[n][1] + bbv.y; *(float2*)&vn[base]    = v;
        v.x = a3[n][0] + bbs.x; v.y = a3[n][1] + bbs.y; *(float2*)&skipn[base] = v;
    }
}

// ---------------------------------------------------------------------------
// K1b: G[n, col] = sum_c q[n, h*64+c] * We[j, h*64+c], col = h*96+j in [0,192).
// Lane owns cols {lane, 64+lane, 128+lane}. 32 nodes/block. G stored bf16.
// ---------------------------------------------------------------------------
__global__ __launch_bounds__(256) void g_kernel(
    const float* __restrict__ qn, const float* __restrict__ We,
    bf16* __restrict__ G)
{
    __shared__ float qs[32 * DD];       // 16 KB
    __shared__ float we_s[96 * 130];    // padded stride 130 -> 49920 B

    const int node0 = blockIdx.x * 32;
    for (int i = threadIdx.x; i < 32 * DD; i += 256) {
        int node = node0 + (i >> 7);
        qs[i] = (node < NN) ? qn[(size_t)node * DD + (i & 127)] : 0.f;
    }
    for (int i = threadIdx.x; i < 96 * 128; i += 256)
        we_s[(i >> 7) * 130 + (i & 127)] = We[i];
    __syncthreads();

    const int wave = threadIdx.x >> 6;
    const int lane = threadIdx.x & 63;
    const int nb = wave * 8;

    // col0 = lane        -> h=0, j=lane
    // col1 = 64+lane     -> lane<32: h=0, j=64+lane ; lane>=32: h=1, j=lane-32
    // col2 = 128+lane    -> h=1, j=32+lane
    const int o0 = lane * 130;
    const int o1 = (lane < 32) ? (64 + lane) * 130 : (lane - 32) * 130 + 64;
    const int o2 = (32 + lane) * 130 + 64;

    float g[8][3];
    #pragma unroll
    for (int n = 0; n < 8; n++) { g[n][0]=0.f; g[n][1]=0.f; g[n][2]=0.f; }

    for (int c = 0; c < 64; c++) {
        float w0 = we_s[o0 + c];
        float w1 = we_s[o1 + c];
        float w2 = we_s[o2 + c];
        #pragma unroll
        for (int n = 0; n < 8; n++) {
            float q0 = qs[(nb + n) * DD + c];
            float q1 = qs[(nb + n) * DD + 64 + c];
            float qm = (lane < 32) ? q0 : q1;
            g[n][0] = fmaf(q0, w0, g[n][0]);
            g[n][1] = fmaf(qm, w1, g[n][1]);
            g[n][2] = fmaf(q1, w2, g[n][2]);
        }
    }

    #pragma unroll 1
    for (int n = 0; n < 8; n++) {
        int node = node0 + nb + n;
        if (node >= NN) break;
        size_t b = (size_t)node * 192;
        G[b + lane]       = __float2bfloat16(g[n][0]);
        G[b + 64 + lane]  = __float2bfloat16(g[n][1]);
        G[b + 128 + lane] = __float2bfloat16(g[n][2]);
    }
}

// --------------------------- sort: histogram --------------------------------
__global__ __launch_bounds__(256) void hist_kernel(
    const int* __restrict__ ei, int* __restrict__ cnt)
{
    int gid = blockIdx.x * 256 + threadIdx.x;
    if (gid < NE) atomicAdd(&cnt[ei[NE + gid]], 1);
}

// --------------------------- sort: scan stage a -----------------------------
__global__ __launch_bounds__(256) void scan_a_kernel(
    const int* __restrict__ cnt, int* __restrict__ bsum)
{
    __shared__ int red[256];
    int gid = blockIdx.x * 256 + threadIdx.x;
    red[threadIdx.x] = (gid < NN) ? cnt[gid] : 0;
    __syncthreads();
    for (int off = 128; off > 0; off >>= 1) {
        if (threadIdx.x < off) red[threadIdx.x] += red[threadIdx.x + off];
        __syncthreads();
    }
    if (threadIdx.x == 0) bsum[blockIdx.x] = red[0];
}

// --------------------------- sort: scan stage b -----------------------------
__global__ __launch_bounds__(256) void scan_b_kernel(
    const int* __restrict__ bsum, int* __restrict__ boff, int* __restrict__ seg)
{
    __shared__ int s[256];
    int t = threadIdx.x;
    s[t] = (t < 196) ? bsum[t] : 0;
    __syncthreads();
    if (t == 0) {
        int run = 0;
        for (int b = 0; b < 196; b++) { int v = s[b]; s[b] = run; run += v; }
        seg[NN] = NE;  // sentinel
    }
    __syncthreads();
    if (t < 196) boff[t] = s[t];
}

// --------------------------- sort: scan stage c -----------------------------
__global__ __launch_bounds__(256) void scan_c_kernel(
    const int* __restrict__ cnt, const int* __restrict__ boff,
    int* __restrict__ seg, int* __restrict__ cur)
{
    __shared__ int s[256];
    int gid = blockIdx.x * 256 + threadIdx.x;
    int v = (gid < NN) ? cnt[gid] : 0;
    s[threadIdx.x] = v;
    __syncthreads();
    for (int off = 1; off < 256; off <<= 1) {
        int t = (threadIdx.x >= off) ? s[threadIdx.x - off] : 0;
        __syncthreads();
        s[threadIdx.x] += t;
        __syncthreads();
    }
    int excl = s[threadIdx.x] - v + boff[blockIdx.x];
    if (gid < NN) { seg[gid] = excl; cur[gid] = excl; }
}

// --------------------------- sort: scatter ----------------------------------
__global__ __launch_bounds__(256) void scatter_kernel(
    const int* __restrict__ ei, int* __restrict__ cur, int* __restrict__ perm)
{
    int gid = blockIdx.x * 256 + threadIdx.x;
    if (gid < NE) {
        int pos = atomicAdd(&cur[ei[NE + gid]], 1);
        perm[pos] = gid;
    }
}

// ---------------------------------------------------------------------------
// K2: one wave per dst node (grid-stride). Register accumulation, no atomics.
//   alpha = (q.k + attr.G[dst]) / 8 ;  ex = exp(alpha)
//   acc += ex * v[src] ; S[h] += ex_h * attr ; denom += ex
// Epilogue: acc += S @ We ; out = acc/denom + skip  (direct final write).
// ---------------------------------------------------------------------------
__global__ __launch_bounds__(256) void edge_kernel(
    const int* __restrict__ ei, const int* __restrict__ et,
    const float* __restrict__ msg,
    const float* __restrict__ Wt, const float* __restrict__ bt,
    const float* __restrict__ We,
    const float* __restrict__ qn, const float* __restrict__ kn,
    const float* __restrict__ vn, const float* __restrict__ skipn,
    const bf16* __restrict__ G,
    const int* __restrict__ seg, const int* __restrict__ perm,
    float* __restrict__ out)
{
    __shared__ float2 we2_s[96 * 64];   // row-major [k][c], 48 KB
    __shared__ float wt_s[TDD], bt_s[TDD];
    const float2* We2 = (const float2*)We;
    for (int i = threadIdx.x; i < 96 * 64; i += 256) we2_s[i] = We2[i];
    if (threadIdx.x < TDD) {
        wt_s[threadIdx.x] = Wt[threadIdx.x];
        bt_s[threadIdx.x] = bt[threadIdx.x];
    }
    __syncthreads();

    const int lane = threadIdx.x & 63;
    const int gw = blockIdx.x * 4 + (threadIdx.x >> 6);
    const int NW = gridDim.x * 4;
    const float wtv = wt_s[lane & 31];
    const float btv = bt_s[lane & 31];
    const int mcol = (lane < 32) ? (32 + lane) : (lane - 32);

    for (int n = gw; n < NN; n += NW) {
        const int s0 = seg[n], s1 = seg[n + 1];
        const size_t nb = (size_t)n * HCC + 2 * lane;
        const float2 q2 = *(const float2*)&qn[nb];
        const size_t gb = (size_t)n * 192;
        float g00 = __bfloat162float(G[gb + lane]);
        float g10 = __bfloat162float(G[gb + 96 + lane]);
        float g01 = 0.f, g11 = 0.f;
        if (lane < 32) {
            g01 = __bfloat162float(G[gb + 64 + lane]);
            g11 = __bfloat162float(G[gb + 160 + lane]);
        }

        float2 acc; acc.x = 0.f; acc.y = 0.f;
        float accd = 0.f;
        float s00 = 0.f, s01 = 0.f, s10 = 0.f, s11 = 0.f;

        for (int i = s0; i < s1; i++) {
            int e = perm[i];
            int src = ei[e];
            float tt = (float)et[e];
            float mg = msg[(size_t)e * MDD + mcol];
            float cs = cosf(tt * wtv + btv);
            float r0 = (lane < 32) ? cs : mg;    // attr[lane]
            float r1 = (lane < 32) ? mg : 0.f;   // attr[64+lane] (lanes<32)

            size_t sb = (size_t)src * HCC + 2 * lane;
            float2 k2 = *(const float2*)&kn[sb];
            float2 v2 = *(const float2*)&vn[sb];

            // q.k partial, reduced within 32-lane head halves
            float p = q2.x * k2.x + q2.y * k2.y;
            p += __shfl_xor(p, 1, 64);  p += __shfl_xor(p, 2, 64);
            p += __shfl_xor(p, 4, 64);  p += __shfl_xor(p, 8, 64);
            p += __shfl_xor(p, 16, 64);
            float qkA = p;
            float qkB = __shfl_xor(qkA, 32, 64);

            // attr . G per head, reduced over all 64 lanes
            float u0 = r0 * g00 + r1 * g01;
            float u1 = r0 * g10 + r1 * g11;
            u0 += __shfl_xor(u0, 1, 64);  u1 += __shfl_xor(u1, 1, 64);
            u0 += __shfl_xor(u0, 2, 64);  u1 += __shfl_xor(u1, 2, 64);
            u0 += __shfl_xor(u0, 4, 64);  u1 += __shfl_xor(u1, 4, 64);
            u0 += __shfl_xor(u0, 8, 64);  u1 += __shfl_xor(u1, 8, 64);
            u0 += __shfl_xor(u0, 16, 64); u1 += __shfl_xor(u1, 16, 64);
            u0 += __shfl_xor(u0, 32, 64); u1 += __shfl_xor(u1, 32, 64);

            float qk0 = (lane < 32) ? qkA : qkB;
            float qk1 = (lane < 32) ? qkB : qkA;
            float ex0 = expf((qk0 + u0) * 0.125f);
            float ex1 = expf((qk1 + u1) * 0.125f);
            float exh = (lane < 32) ? ex0 : ex1;

            acc.x = fmaf(exh, v2.x, acc.x);
            acc.y = fmaf(exh, v2.y, acc.y);
            accd += exh;
            s00 = fmaf(ex0, r0, s00); s01 = fmaf(ex0, r1, s01);
            s10 = fmaf(ex1, r0, s10); s11 = fmaf(ex1, r1, s11);
        }

        // epilogue: acc += S[h(lane)] @ We   (S[h][k] broadcast via readlane)
        float dn = accd + 1e-16f;
        #pragma unroll
        for (int k = 0; k < 96; k++) {
            float b0 = (k < 64) ? __shfl(s00, k, 64) : __shfl(s01, k - 64, 64);
            float b1 = (k < 64) ? __shfl(s10, k, 64) : __shfl(s11, k - 64, 64);
            float bs = (lane < 32) ? b0 : b1;
            float2 w = we2_s[k * 64 + lane];
            acc.x = fmaf(bs, w.x, acc.x);
            acc.y = fmaf(bs, w.y, acc.y);
        }

        float2 sk = *(const float2*)&skipn[nb];
        float2 o;
        o.x = acc.x / dn + sk.x;
        o.y = acc.y / dn + sk.y;
        *(float2*)&out[nb] = o;
    }
}

extern "C" void kernel_launch(void* const* d_in, const int* in_sizes, int n_in,
                              void* d_out, int out_size, void* d_ws, size_t ws_size,
                              hipStream_t stream) {
    const float* x   = (const float*)d_in[0];
    const int* ei    = (const int*)d_in[1];
    const int* et    = (const int*)d_in[2];
    const float* msg = (const float*)d_in[3];
    const float* Wt  = (const float*)d_in[4];
    const float* bt  = (const float*)d_in[5];
    const float* Wq  = (const float*)d_in[6];
    const float* bq  = (const float*)d_in[7];
    const float* Wk  = (const float*)d_in[8];
    const float* bk  = (const float*)d_in[9];
    const float* Wv  = (const float*)d_in[10];
    const float* bv  = (const float*)d_in[11];
    const float* We  = (const float*)d_in[12];
    const float* Wsk = (const float*)d_in[13];
    const float* bsk = (const float*)d_in[14];

    const size_t nf = (size_t)NN * HCC;       // 6.4M floats
    float* qn    = (float*)d_ws;
    float* kn    = qn + nf;
    float* vn    = kn + nf;
    float* skipn = vn + nf;
    bf16* G      = (bf16*)(skipn + nf);       // 50000*192 bf16
    int* cnt     = (int*)(G + (size_t)NN * 192);
    int* seg     = cnt + NN;                  // NN+1 entries
    int* cur     = seg + NN + 1;
    int* perm    = cur + NN;
    int* bsum    = perm + NE;
    int* boff    = bsum + 256;
    size_t need  = (size_t)((char*)(boff + 256) - (char*)d_ws);
    if (ws_size < need) return;

    node_proj_kernel<<<(NN + 63) / 64, 256, 0, stream>>>(
        x, Wq, bq, Wk, bk, Wv, bv, Wsk, bsk, qn, kn, vn, skipn, cnt);
    g_kernel<<<(NN + 31) / 32, 256, 0, stream>>>(qn, We, G);
    hist_kernel<<<(NE + 255) / 256, 256, 0, stream>>>(ei, cnt);
    scan_a_kernel<<<196, 256, 0, stream>>>(cnt, bsum);
    scan_b_kernel<<<1, 256, 0, stream>>>(bsum, boff, seg);
    scan_c_kernel<<<196, 256, 0, stream>>>(cnt, boff, seg, cur);
    scatter_kernel<<<(NE + 255) / 256, 256, 0, stream>>>(ei, cur, perm);
    edge_kernel<<<1563, 256, 0, stream>>>(
        ei, et, msg, Wt, bt, We, qn, kn, vn, skipn, G, seg, perm, (float*)d_out);
}

// Round 4
// 1145.297 us; speedup vs baseline: 2.3801x; 1.4667x over previous
//
#include <hip/hip_runtime.h>
#include <hip/hip_bf16.h>

#define NN 50000
#define NE 500000
#define DD 128
#define HCC 128
#define TDD 32
#define MDD 64

typedef __hip_bfloat16 bf16;

__device__ __forceinline__ float2 bf2x(unsigned u) {
    union { unsigned v; float f; } a, b;
    a.v = u << 16; b.v = u & 0xffff0000u;
    float2 r; r.x = a.f; r.y = b.f; return r;
}

__device__ __forceinline__ unsigned pack_bf(float2 w) {
    union { __hip_bfloat162 h; unsigned u; } cv;
    cv.h = __float22bfloat162_rn(w);
    return cv.u;
}

// ---------------------------------------------------------------------------
// K1: node projections q/k/v = x@W+b (f32), skip written DIRECTLY into out.
// Also zeroes cnt[]. 64 nodes/block; wave=16 nodes; lane owns 2 cols.
// ---------------------------------------------------------------------------
__global__ __launch_bounds__(256) void node_proj_kernel(
    const float* __restrict__ x,
    const float* __restrict__ Wq, const float* __restrict__ bq,
    const float* __restrict__ Wk, const float* __restrict__ bk,
    const float* __restrict__ Wv, const float* __restrict__ bv,
    const float* __restrict__ Wsk, const float* __restrict__ bsk,
    float* __restrict__ qn, float* __restrict__ kn, float* __restrict__ vn,
    float* __restrict__ outp, int* __restrict__ cnt)
{
    int gid = blockIdx.x * 256 + threadIdx.x;
    if (gid < NN) cnt[gid] = 0;

    __shared__ float xs[64 * DD];  // 32 KB
    const int node0 = blockIdx.x * 64;
    for (int i = threadIdx.x; i < 64 * DD; i += 256) {
        int node = node0 + (i >> 7);
        xs[i] = (node < NN) ? x[(size_t)node * DD + (i & 127)] : 0.f;
    }
    __syncthreads();

    const int wave = threadIdx.x >> 6;
    const int lane = threadIdx.x & 63;
    const int nb = wave * 16;

    float a0[16][2], a1[16][2], a2[16][2], a3[16][2];
    #pragma unroll
    for (int n = 0; n < 16; n++) {
        a0[n][0]=0.f; a0[n][1]=0.f; a1[n][0]=0.f; a1[n][1]=0.f;
        a2[n][0]=0.f; a2[n][1]=0.f; a3[n][0]=0.f; a3[n][1]=0.f;
    }

    const float2* W2q = (const float2*)Wq;
    const float2* W2k = (const float2*)Wk;
    const float2* W2v = (const float2*)Wv;
    const float2* W2s = (const float2*)Wsk;

    for (int k = 0; k < DD; k++) {
        float2 wq = W2q[k * 64 + lane];
        float2 wk = W2k[k * 64 + lane];
        float2 wv = W2v[k * 64 + lane];
        float2 ws = W2s[k * 64 + lane];
        const float* xcol = &xs[nb * DD + k];
        #pragma unroll
        for (int n = 0; n < 16; n++) {
            float xb = xcol[n * DD];
            a0[n][0] = fmaf(xb, wq.x, a0[n][0]); a0[n][1] = fmaf(xb, wq.y, a0[n][1]);
            a1[n][0] = fmaf(xb, wk.x, a1[n][0]); a1[n][1] = fmaf(xb, wk.y, a1[n][1]);
            a2[n][0] = fmaf(xb, wv.x, a2[n][0]); a2[n][1] = fmaf(xb, wv.y, a2[n][1]);
            a3[n][0] = fmaf(xb, ws.x, a3[n][0]); a3[n][1] = fmaf(xb, ws.y, a3[n][1]);
        }
    }

    float2 bbq = ((const float2*)bq)[lane];
    float2 bbk = ((const float2*)bk)[lane];
    float2 bbv = ((const float2*)bv)[lane];
    float2 bbs = ((const float2*)bsk)[lane];

    #pragma unroll 1
    for (int n = 0; n < 16; n++) {
        int node = node0 + nb + n;
        if (node >= NN) break;
        size_t base = (size_t)node * HCC + lane * 2;
        float2 v;
        v.x = a0[n][0] + bbq.x; v.y = a0[n][1] + bbq.y; *(float2*)&qn[base]   = v;
        v.x = a1[n][0] + bbk.x; v.y = a1[n][1] + bbk.y; *(float2*)&kn[base]   = v;
        v.x = a2[n][0] + bbv.x; v.y = a2[n][1] + bbv.y; *(float2*)&vn[base]   = v;
        v.x = a3[n][0] + bbs.x; v.y = a3[n][1] + bbs.y; *(float2*)&outp[base] = v;
    }
}

// ---------------------------------------------------------------------------
// K1b: G[n, h*96+j] = sum_c q[n,h*64+c] * We[j, h*64+c]   (bf16 out)
// ---------------------------------------------------------------------------
__global__ __launch_bounds__(256) void g_kernel(
    const float* __restrict__ qn, const float* __restrict__ We,
    bf16* __restrict__ G)
{
    __shared__ float qs[32 * DD];       // 16 KB
    __shared__ float we_s[96 * 130];    // padded

    const int node0 = blockIdx.x * 32;
    for (int i = threadIdx.x; i < 32 * DD; i += 256) {
        int node = node0 + (i >> 7);
        qs[i] = (node < NN) ? qn[(size_t)node * DD + (i & 127)] : 0.f;
    }
    for (int i = threadIdx.x; i < 96 * 128; i += 256)
        we_s[(i >> 7) * 130 + (i & 127)] = We[i];
    __syncthreads();

    const int wave = threadIdx.x >> 6;
    const int lane = threadIdx.x & 63;
    const int nb = wave * 8;

    const int o0 = lane * 130;
    const int o1 = (lane < 32) ? (64 + lane) * 130 : (lane - 32) * 130 + 64;
    const int o2 = (32 + lane) * 130 + 64;

    float g[8][3];
    #pragma unroll
    for (int n = 0; n < 8; n++) { g[n][0]=0.f; g[n][1]=0.f; g[n][2]=0.f; }

    for (int c = 0; c < 64; c++) {
        float w0 = we_s[o0 + c];
        float w1 = we_s[o1 + c];
        float w2 = we_s[o2 + c];
        #pragma unroll
        for (int n = 0; n < 8; n++) {
            float q0 = qs[(nb + n) * DD + c];
            float q1 = qs[(nb + n) * DD + 64 + c];
            float qm = (lane < 32) ? q0 : q1;
            g[n][0] = fmaf(q0, w0, g[n][0]);
            g[n][1] = fmaf(qm, w1, g[n][1]);
            g[n][2] = fmaf(q1, w2, g[n][2]);
        }
    }

    #pragma unroll 1
    for (int n = 0; n < 8; n++) {
        int node = node0 + nb + n;
        if (node >= NN) break;
        size_t b = (size_t)node * 192;
        G[b + lane]       = __float2bfloat16(g[n][0]);
        G[b + 64 + lane]  = __float2bfloat16(g[n][1]);
        G[b + 128 + lane] = __float2bfloat16(g[n][2]);
    }
}

// --------------------------- sort pipeline ----------------------------------
__global__ __launch_bounds__(256) void hist_kernel(
    const int* __restrict__ ei, int* __restrict__ cnt)
{
    int gid = blockIdx.x * 256 + threadIdx.x;
    if (gid < NE) atomicAdd(&cnt[ei[NE + gid]], 1);
}

__global__ __launch_bounds__(256) void scan_a_kernel(
    const int* __restrict__ cnt, int* __restrict__ bsum)
{
    __shared__ int red[256];
    int gid = blockIdx.x * 256 + threadIdx.x;
    red[threadIdx.x] = (gid < NN) ? cnt[gid] : 0;
    __syncthreads();
    for (int off = 128; off > 0; off >>= 1) {
        if (threadIdx.x < off) red[threadIdx.x] += red[threadIdx.x + off];
        __syncthreads();
    }
    if (threadIdx.x == 0) bsum[blockIdx.x] = red[0];
}

__global__ __launch_bounds__(256) void scan_b_kernel(
    const int* __restrict__ bsum, int* __restrict__ boff, int* __restrict__ seg)
{
    __shared__ int s[256];
    int t = threadIdx.x;
    s[t] = (t < 196) ? bsum[t] : 0;
    __syncthreads();
    if (t == 0) {
        int run = 0;
        for (int b = 0; b < 196; b++) { int v = s[b]; s[b] = run; run += v; }
        seg[NN] = NE;
    }
    __syncthreads();
    if (t < 196) boff[t] = s[t];
}

__global__ __launch_bounds__(256) void scan_c_kernel(
    const int* __restrict__ cnt, const int* __restrict__ boff,
    int* __restrict__ seg, int* __restrict__ cur)
{
    __shared__ int s[256];
    int gid = blockIdx.x * 256 + threadIdx.x;
    int v = (gid < NN) ? cnt[gid] : 0;
    s[threadIdx.x] = v;
    __syncthreads();
    for (int off = 1; off < 256; off <<= 1) {
        int t = (threadIdx.x >= off) ? s[threadIdx.x - off] : 0;
        __syncthreads();
        s[threadIdx.x] += t;
        __syncthreads();
    }
    int excl = s[threadIdx.x] - v + boff[blockIdx.x];
    if (gid < NN) { seg[gid] = excl; cur[gid] = excl; }
}

// scatter + pre-gather of per-edge data into sorted order
__global__ __launch_bounds__(256) void scatter_kernel(
    const int* __restrict__ ei, const int* __restrict__ et,
    int* __restrict__ cur, int* __restrict__ perm,
    int* __restrict__ esrc, int* __restrict__ edst, float* __restrict__ etim)
{
    int gid = blockIdx.x * 256 + threadIdx.x;
    if (gid < NE) {
        int d = ei[NE + gid];
        int pos = atomicAdd(&cur[d], 1);
        perm[pos] = gid;
        esrc[pos] = ei[gid];
        edst[pos] = d;
        etim[pos] = (float)et[gid];
    }
}

// ---------------------------------------------------------------------------
// K2a: one THREAD per sorted edge. Pure scalar f32 dots, no cross-lane ops.
//   ex_h = exp((q[dst].k[src]  +  attr.G[dst,h]) / 8)
// attr = [cos(t*wt+bt) (32), msg (64)]. Sorted order -> q/G rows L1-resident.
// ---------------------------------------------------------------------------
__global__ __launch_bounds__(256) void score_kernel(
    const int* __restrict__ esrc, const int* __restrict__ edst,
    const float* __restrict__ etim, const int* __restrict__ perm,
    const float* __restrict__ msg,
    const float* __restrict__ Wt, const float* __restrict__ bt,
    const float* __restrict__ qn, const float* __restrict__ kn,
    const bf16* __restrict__ G, float2* __restrict__ exv)
{
    __shared__ float wt_s[TDD], bt_s[TDD];
    if (threadIdx.x < TDD) {
        wt_s[threadIdx.x] = Wt[threadIdx.x];
        bt_s[threadIdx.x] = bt[threadIdx.x];
    }
    __syncthreads();

    int i = blockIdx.x * 256 + threadIdx.x;
    if (i >= NE) return;

    int src = esrc[i], dst = edst[i], e = perm[i];
    float t = etim[i];

    const float4* qp = (const float4*)(qn + (size_t)dst * DD);
    const float4* kp = (const float4*)(kn + (size_t)src * DD);
    float qk0 = 0.f, qk1 = 0.f;
    #pragma unroll
    for (int c = 0; c < 16; c++) {
        float4 a = qp[c], b = kp[c];
        qk0 = fmaf(a.x, b.x, qk0); qk0 = fmaf(a.y, b.y, qk0);
        qk0 = fmaf(a.z, b.z, qk0); qk0 = fmaf(a.w, b.w, qk0);
    }
    #pragma unroll
    for (int c = 16; c < 32; c++) {
        float4 a = qp[c], b = kp[c];
        qk1 = fmaf(a.x, b.x, qk1); qk1 = fmaf(a.y, b.y, qk1);
        qk1 = fmaf(a.z, b.z, qk1); qk1 = fmaf(a.w, b.w, qk1);
    }

    const uint4* gp = (const uint4*)(G + (size_t)dst * 192);  // 8 bf16 per uint4
    float u0 = 0.f, u1 = 0.f;

    // cos part: G[0..31] (h0) = gp[0..3], G[96..127] (h1) = gp[12..15]
    #pragma unroll
    for (int c = 0; c < 4; c++) {
        uint4 g0 = gp[c], g1 = gp[12 + c];
        float cj[8];
        #pragma unroll
        for (int j = 0; j < 8; j++)
            cj[j] = __cosf(fmaf(t, wt_s[8 * c + j], bt_s[8 * c + j]));
        float2 p;
        p = bf2x(g0.x); u0 = fmaf(cj[0], p.x, u0); u0 = fmaf(cj[1], p.y, u0);
        p = bf2x(g0.y); u0 = fmaf(cj[2], p.x, u0); u0 = fmaf(cj[3], p.y, u0);
        p = bf2x(g0.z); u0 = fmaf(cj[4], p.x, u0); u0 = fmaf(cj[5], p.y, u0);
        p = bf2x(g0.w); u0 = fmaf(cj[6], p.x, u0); u0 = fmaf(cj[7], p.y, u0);
        p = bf2x(g1.x); u1 = fmaf(cj[0], p.x, u1); u1 = fmaf(cj[1], p.y, u1);
        p = bf2x(g1.y); u1 = fmaf(cj[2], p.x, u1); u1 = fmaf(cj[3], p.y, u1);
        p = bf2x(g1.z); u1 = fmaf(cj[4], p.x, u1); u1 = fmaf(cj[5], p.y, u1);
        p = bf2x(g1.w); u1 = fmaf(cj[6], p.x, u1); u1 = fmaf(cj[7], p.y, u1);
    }

    // msg part: G[32..95] (h0) = gp[4..11], G[128..191] (h1) = gp[16..23]
    const float4* mp = (const float4*)(msg + (size_t)e * MDD);
    #pragma unroll
    for (int c = 0; c < 8; c++) {
        float4 ma = mp[2 * c], mb = mp[2 * c + 1];
        uint4 g0 = gp[4 + c], g1 = gp[16 + c];
        float2 p;
        p = bf2x(g0.x); u0 = fmaf(ma.x, p.x, u0); u0 = fmaf(ma.y, p.y, u0);
        p = bf2x(g0.y); u0 = fmaf(ma.z, p.x, u0); u0 = fmaf(ma.w, p.y, u0);
        p = bf2x(g0.z); u0 = fmaf(mb.x, p.x, u0); u0 = fmaf(mb.y, p.y, u0);
        p = bf2x(g0.w); u0 = fmaf(mb.z, p.x, u0); u0 = fmaf(mb.w, p.y, u0);
        p = bf2x(g1.x); u1 = fmaf(ma.x, p.x, u1); u1 = fmaf(ma.y, p.y, u1);
        p = bf2x(g1.y); u1 = fmaf(ma.z, p.x, u1); u1 = fmaf(ma.w, p.y, u1);
        p = bf2x(g1.z); u1 = fmaf(mb.x, p.x, u1); u1 = fmaf(mb.y, p.y, u1);
        p = bf2x(g1.w); u1 = fmaf(mb.z, p.x, u1); u1 = fmaf(mb.w, p.y, u1);
    }

    float2 ex;
    ex.x = __expf((qk0 + u0) * 0.125f);
    ex.y = __expf((qk1 + u1) * 0.125f);
    exv[i] = ex;
}

// ---------------------------------------------------------------------------
// K2b: wave per dst node. No shuffles / exp in the edge loop (ex precomputed).
//   acc += ex_h * v[src] ; S_h += ex_h * attr ; dn += ex_h
// Epilogue: acc += S @ We (bf16 LDS) ; out = acc/dn + out(skip, from K1).
// ---------------------------------------------------------------------------
__global__ __launch_bounds__(256) void agg_kernel(
    const int* __restrict__ esrc, const int* __restrict__ perm,
    const float* __restrict__ etim,
    const float* __restrict__ msg,
    const float* __restrict__ Wt, const float* __restrict__ bt,
    const float* __restrict__ We,
    const float* __restrict__ vn, const float2* __restrict__ exv,
    const int* __restrict__ seg,
    float* __restrict__ outp)
{
    __shared__ unsigned we_u[96 * 64];   // bf16-pair packed, 24 KB
    __shared__ float wt_s[TDD], bt_s[TDD];
    const float2* We2 = (const float2*)We;
    for (int i = threadIdx.x; i < 96 * 64; i += 256) we_u[i] = pack_bf(We2[i]);
    if (threadIdx.x < TDD) {
        wt_s[threadIdx.x] = Wt[threadIdx.x];
        bt_s[threadIdx.x] = bt[threadIdx.x];
    }
    __syncthreads();

    const int lane = threadIdx.x & 63;
    const int gw = blockIdx.x * 4 + (threadIdx.x >> 6);
    const int NW = gridDim.x * 4;
    const float wtv = wt_s[lane & 31];
    const float btv = bt_s[lane & 31];
    const int mcol = (lane < 32) ? (32 + lane) : (lane - 32);

    for (int n = gw; n < NN; n += NW) {
        const int s0 = seg[n], s1 = seg[n + 1];

        float2 acc; acc.x = 0.f; acc.y = 0.f;
        float accd = 0.f;
        float s00 = 0.f, s01 = 0.f, s10 = 0.f, s11 = 0.f;

        for (int i = s0; i < s1; i++) {
            int e = perm[i];
            int src = esrc[i];
            float2 ex = exv[i];
            float t = etim[i];
            float mg = msg[(size_t)e * MDD + mcol];
            float cs = __cosf(fmaf(t, wtv, btv));
            float r0 = (lane < 32) ? cs : mg;
            float r1 = (lane < 32) ? mg : 0.f;
            float2 v2 = *(const float2*)&vn[(size_t)src * HCC + 2 * lane];
            float exh = (lane < 32) ? ex.x : ex.y;

            acc.x = fmaf(exh, v2.x, acc.x);
            acc.y = fmaf(exh, v2.y, acc.y);
            accd += exh;
            s00 = fmaf(ex.x, r0, s00); s01 = fmaf(ex.x, r1, s01);
            s10 = fmaf(ex.y, r0, s10); s11 = fmaf(ex.y, r1, s11);
        }

        float dn = accd + 1e-16f;
        #pragma unroll
        for (int k = 0; k < 96; k++) {
            float b0 = (k < 64) ? __shfl(s00, k, 64) : __shfl(s01, k - 64, 64);
            float b1 = (k < 64) ? __shfl(s10, k, 64) : __shfl(s11, k - 64, 64);
            float bs = (lane < 32) ? b0 : b1;
            float2 w = bf2x(we_u[k * 64 + lane]);
            acc.x = fmaf(bs, w.x, acc.x);
            acc.y = fmaf(bs, w.y, acc.y);
        }

        size_t nb = (size_t)n * HCC + 2 * lane;
        float2 sk = *(const float2*)&outp[nb];   // skip written by node_proj
        float2 o;
        o.x = acc.x / dn + sk.x;
        o.y = acc.y / dn + sk.y;
        *(float2*)&outp[nb] = o;
    }
}

extern "C" void kernel_launch(void* const* d_in, const int* in_sizes, int n_in,
                              void* d_out, int out_size, void* d_ws, size_t ws_size,
                              hipStream_t stream) {
    const float* x   = (const float*)d_in[0];
    const int* ei    = (const int*)d_in[1];
    const int* et    = (const int*)d_in[2];
    const float* msg = (const float*)d_in[3];
    const float* Wt  = (const float*)d_in[4];
    const float* bt  = (const float*)d_in[5];
    const float* Wq  = (const float*)d_in[6];
    const float* bq  = (const float*)d_in[7];
    const float* Wk  = (const float*)d_in[8];
    const float* bk  = (const float*)d_in[9];
    const float* Wv  = (const float*)d_in[10];
    const float* bv  = (const float*)d_in[11];
    const float* We  = (const float*)d_in[12];
    const float* Wsk = (const float*)d_in[13];
    const float* bsk = (const float*)d_in[14];

    const size_t nf = (size_t)NN * HCC;
    float* qn    = (float*)d_ws;
    float* kn    = qn + nf;
    float* vn    = kn + nf;
    bf16*  G     = (bf16*)(vn + nf);              // NN*192 bf16
    float2* exv  = (float2*)(G + (size_t)NN * 192);
    float* etim  = (float*)(exv + NE);
    int* cnt     = (int*)(etim + NE);
    int* seg     = cnt + NN;                      // NN+1
    int* cur     = seg + NN + 1;
    int* perm    = cur + NN;
    int* esrc    = perm + NE;
    int* edst    = esrc + NE;
    int* bsum    = edst + NE;
    int* boff    = bsum + 256;
    size_t need  = (size_t)((char*)(boff + 256) - (char*)d_ws);
    if (ws_size < need) return;

    float* outp = (float*)d_out;

    node_proj_kernel<<<(NN + 63) / 64, 256, 0, stream>>>(
        x, Wq, bq, Wk, bk, Wv, bv, Wsk, bsk, qn, kn, vn, outp, cnt);
    g_kernel<<<(NN + 31) / 32, 256, 0, stream>>>(qn, We, G);
    hist_kernel<<<(NE + 255) / 256, 256, 0, stream>>>(ei, cnt);
    scan_a_kernel<<<196, 256, 0, stream>>>(cnt, bsum);
    scan_b_kernel<<<1, 256, 0, stream>>>(bsum, boff, seg);
    scan_c_kernel<<<196, 256, 0, stream>>>(cnt, boff, seg, cur);
    scatter_kernel<<<(NE + 255) / 256, 256, 0, stream>>>(
        ei, et, cur, perm, esrc, edst, etim);
    score_kernel<<<(NE + 255) / 256, 256, 0, stream>>>(
        esrc, edst, etim, perm, msg, Wt, bt, qn, kn, G, exv);
    agg_kernel<<<3125, 256, 0, stream>>>(
        esrc, perm, etim, msg, Wt, bt, We, vn, exv, seg, outp);
}

// Round 5
// 812.829 us; speedup vs baseline: 3.3536x; 1.4090x over previous
//
#include <hip/hip_runtime.h>
#include <hip/hip_bf16.h>

#define NN 50000
#define NE 500000
#define DD 128
#define HCC 128
#define TDD 32
#define MDD 64

typedef __hip_bfloat16 bf16;

__device__ __forceinline__ float2 bf2x(unsigned u) {
    union { unsigned v; float f; } a, b;
    a.v = u << 16; b.v = u & 0xffff0000u;
    float2 r; r.x = a.f; r.y = b.f; return r;
}

// ---------------------------------------------------------------------------
// K1: node projections q/k/v = x@W+b (f32), skip written DIRECTLY into out.
// Transposed LDS x-tile: xt[k][node] (pad 68) -> 4x ds_read_b128 broadcast/k.
// ---------------------------------------------------------------------------
__global__ __launch_bounds__(256) void node_proj_kernel(
    const float* __restrict__ x,
    const float* __restrict__ Wq, const float* __restrict__ bq,
    const float* __restrict__ Wk, const float* __restrict__ bk,
    const float* __restrict__ Wv, const float* __restrict__ bv,
    const float* __restrict__ Wsk, const float* __restrict__ bsk,
    float* __restrict__ qn, float* __restrict__ kn, float* __restrict__ vn,
    float* __restrict__ outp, int* __restrict__ cnt)
{
    int gid = blockIdx.x * 256 + threadIdx.x;
    if (gid < NN) cnt[gid] = 0;

    __shared__ float xt[DD * 68];  // 34.8 KB, xt[k*68 + node]
    const int node0 = blockIdx.x * 64;
    for (int i = threadIdx.x; i < 64 * DD; i += 256) {
        int node = i >> 7, k = i & 127;
        int gn = node0 + node;
        xt[k * 68 + node] = (gn < NN) ? x[(size_t)gn * DD + k] : 0.f;
    }
    __syncthreads();

    const int wave = threadIdx.x >> 6;
    const int lane = threadIdx.x & 63;
    const int nb = wave * 16;

    float a0[16][2], a1[16][2], a2[16][2], a3[16][2];
    #pragma unroll
    for (int n = 0; n < 16; n++) {
        a0[n][0]=0.f; a0[n][1]=0.f; a1[n][0]=0.f; a1[n][1]=0.f;
        a2[n][0]=0.f; a2[n][1]=0.f; a3[n][0]=0.f; a3[n][1]=0.f;
    }

    const float2* W2q = (const float2*)Wq;
    const float2* W2k = (const float2*)Wk;
    const float2* W2v = (const float2*)Wv;
    const float2* W2s = (const float2*)Wsk;

    for (int k = 0; k < DD; k++) {
        float2 wq = W2q[k * 64 + lane];
        float2 wk = W2k[k * 64 + lane];
        float2 wv = W2v[k * 64 + lane];
        float2 ws = W2s[k * 64 + lane];
        const float* xr = &xt[k * 68 + nb];
        float xv[16];
        *(float4*)&xv[0]  = *(const float4*)(xr);
        *(float4*)&xv[4]  = *(const float4*)(xr + 4);
        *(float4*)&xv[8]  = *(const float4*)(xr + 8);
        *(float4*)&xv[12] = *(const float4*)(xr + 12);
        #pragma unroll
        for (int n = 0; n < 16; n++) {
            float xb = xv[n];
            a0[n][0] = fmaf(xb, wq.x, a0[n][0]); a0[n][1] = fmaf(xb, wq.y, a0[n][1]);
            a1[n][0] = fmaf(xb, wk.x, a1[n][0]); a1[n][1] = fmaf(xb, wk.y, a1[n][1]);
            a2[n][0] = fmaf(xb, wv.x, a2[n][0]); a2[n][1] = fmaf(xb, wv.y, a2[n][1]);
            a3[n][0] = fmaf(xb, ws.x, a3[n][0]); a3[n][1] = fmaf(xb, ws.y, a3[n][1]);
        }
    }

    float2 bbq = ((const float2*)bq)[lane];
    float2 bbk = ((const float2*)bk)[lane];
    float2 bbv = ((const float2*)bv)[lane];
    float2 bbs = ((const float2*)bsk)[lane];

    #pragma unroll 1
    for (int n = 0; n < 16; n++) {
        int node = node0 + nb + n;
        if (node >= NN) break;
        size_t base = (size_t)node * HCC + lane * 2;
        float2 v;
        v.x = a0[n][0] + bbq.x; v.y = a0[n][1] + bbq.y; *(float2*)&qn[base]   = v;
        v.x = a1[n][0] + bbk.x; v.y = a1[n][1] + bbk.y; *(float2*)&kn[base]   = v;
        v.x = a2[n][0] + bbv.x; v.y = a2[n][1] + bbv.y; *(float2*)&vn[base]   = v;
        v.x = a3[n][0] + bbs.x; v.y = a3[n][1] + bbs.y; *(float2*)&outp[base] = v;
    }
}

// ---------------------------------------------------------------------------
// K1b: G[n, h*96+j] = sum_c q[n,h*64+c] * We[j, h*64+c]   (bf16 out)
// Transposed q-tile qt[c][node] (pad 36) -> b128 broadcast reads.
// ---------------------------------------------------------------------------
__global__ __launch_bounds__(256) void g_kernel(
    const float* __restrict__ qn, const float* __restrict__ We,
    bf16* __restrict__ G)
{
    __shared__ float qt[DD * 36];       // 18.4 KB, qt[c*36 + node]
    __shared__ float we_s[96 * 130];    // 49.9 KB

    const int node0 = blockIdx.x * 32;
    for (int i = threadIdx.x; i < 32 * DD; i += 256) {
        int n = i >> 7, c = i & 127;
        int gn = node0 + n;
        qt[c * 36 + n] = (gn < NN) ? qn[(size_t)gn * DD + c] : 0.f;
    }
    for (int i = threadIdx.x; i < 96 * 128; i += 256)
        we_s[(i >> 7) * 130 + (i & 127)] = We[i];
    __syncthreads();

    const int wave = threadIdx.x >> 6;
    const int lane = threadIdx.x & 63;
    const int nb = wave * 8;
    const bool half0 = (lane < 32);

    const int o0 = lane * 130;
    const int o1 = half0 ? (64 + lane) * 130 : (lane - 32) * 130 + 64;
    const int o2 = (32 + lane) * 130 + 64;

    float g[8][3];
    #pragma unroll
    for (int n = 0; n < 8; n++) { g[n][0]=0.f; g[n][1]=0.f; g[n][2]=0.f; }

    for (int c = 0; c < 64; c++) {
        float w0 = we_s[o0 + c];
        float w1 = we_s[o1 + c];
        float w2 = we_s[o2 + c];
        float q0v[8], q1v[8];
        *(float4*)&q0v[0] = *(const float4*)&qt[c * 36 + nb];
        *(float4*)&q0v[4] = *(const float4*)&qt[c * 36 + nb + 4];
        *(float4*)&q1v[0] = *(const float4*)&qt[(64 + c) * 36 + nb];
        *(float4*)&q1v[4] = *(const float4*)&qt[(64 + c) * 36 + nb + 4];
        #pragma unroll
        for (int n = 0; n < 8; n++) {
            float qm = half0 ? q0v[n] : q1v[n];
            g[n][0] = fmaf(q0v[n], w0, g[n][0]);
            g[n][1] = fmaf(qm,     w1, g[n][1]);
            g[n][2] = fmaf(q1v[n], w2, g[n][2]);
        }
    }

    #pragma unroll 1
    for (int n = 0; n < 8; n++) {
        int node = node0 + nb + n;
        if (node >= NN) break;
        size_t b = (size_t)node * 192;
        G[b + lane]       = __float2bfloat16(g[n][0]);
        G[b + 64 + lane]  = __float2bfloat16(g[n][1]);
        G[b + 128 + lane] = __float2bfloat16(g[n][2]);
    }
}

// --------------------------- sort pipeline ----------------------------------
__global__ __launch_bounds__(256) void hist_kernel(
    const int* __restrict__ ei, int* __restrict__ cnt)
{
    int gid = blockIdx.x * 256 + threadIdx.x;
    if (gid < NE) atomicAdd(&cnt[ei[NE + gid]], 1);
}

__global__ __launch_bounds__(256) void scan_a_kernel(
    const int* __restrict__ cnt, int* __restrict__ bsum)
{
    __shared__ int red[256];
    int gid = blockIdx.x * 256 + threadIdx.x;
    red[threadIdx.x] = (gid < NN) ? cnt[gid] : 0;
    __syncthreads();
    for (int off = 128; off > 0; off >>= 1) {
        if (threadIdx.x < off) red[threadIdx.x] += red[threadIdx.x + off];
        __syncthreads();
    }
    if (threadIdx.x == 0) bsum[blockIdx.x] = red[0];
}

__global__ __launch_bounds__(256) void scan_b_kernel(
    const int* __restrict__ bsum, int* __restrict__ boff, int* __restrict__ seg)
{
    __shared__ int s[256];
    int t = threadIdx.x;
    s[t] = (t < 196) ? bsum[t] : 0;
    __syncthreads();
    if (t == 0) {
        int run = 0;
        for (int b = 0; b < 196; b++) { int v = s[b]; s[b] = run; run += v; }
        seg[NN] = NE;
    }
    __syncthreads();
    if (t < 196) boff[t] = s[t];
}

__global__ __launch_bounds__(256) void scan_c_kernel(
    const int* __restrict__ cnt, const int* __restrict__ boff,
    int* __restrict__ seg, int* __restrict__ cur)
{
    __shared__ int s[256];
    int gid = blockIdx.x * 256 + threadIdx.x;
    int v = (gid < NN) ? cnt[gid] : 0;
    s[threadIdx.x] = v;
    __syncthreads();
    for (int off = 1; off < 256; off <<= 1) {
        int t = (threadIdx.x >= off) ? s[threadIdx.x - off] : 0;
        __syncthreads();
        s[threadIdx.x] += t;
        __syncthreads();
    }
    int excl = s[threadIdx.x] - v + boff[blockIdx.x];
    if (gid < NN) { seg[gid] = excl; cur[gid] = excl; }
}

__global__ __launch_bounds__(256) void scatter_kernel(
    const int* __restrict__ ei, const int* __restrict__ et,
    int* __restrict__ cur, int* __restrict__ perm,
    int* __restrict__ esrc, int* __restrict__ edst, float* __restrict__ etim)
{
    int gid = blockIdx.x * 256 + threadIdx.x;
    if (gid < NE) {
        int d = ei[NE + gid];
        int pos = atomicAdd(&cur[d], 1);
        perm[pos] = gid;
        esrc[pos] = ei[gid];
        edst[pos] = d;
        etim[pos] = (float)et[gid];
    }
}

// ----------------- msg pre-gather into sorted order (bf16) ------------------
__global__ __launch_bounds__(256) void msg_gather_kernel(
    const float* __restrict__ msg, const int* __restrict__ perm,
    bf16* __restrict__ emsg)
{
    size_t idx = (size_t)blockIdx.x * 256 + threadIdx.x;
    if (idx >= (size_t)NE * MDD) return;
    int i = (int)(idx >> 6);
    int c = (int)(idx & 63);
    emsg[idx] = __float2bfloat16(msg[((size_t)perm[i] << 6) + c]);
}

// ---------------------------------------------------------------------------
// K2a: one THREAD per sorted edge: ex_h = exp((q[dst].k[src] + attr.G[dst,h])/8)
// ---------------------------------------------------------------------------
__global__ __launch_bounds__(256) void score_kernel(
    const int* __restrict__ esrc, const int* __restrict__ edst,
    const float* __restrict__ etim,
    const bf16* __restrict__ emsg,
    const float* __restrict__ Wt, const float* __restrict__ bt,
    const float* __restrict__ qn, const float* __restrict__ kn,
    const bf16* __restrict__ G, float2* __restrict__ exv)
{
    __shared__ float wt_s[TDD], bt_s[TDD];
    if (threadIdx.x < TDD) {
        wt_s[threadIdx.x] = Wt[threadIdx.x];
        bt_s[threadIdx.x] = bt[threadIdx.x];
    }
    __syncthreads();

    int i = blockIdx.x * 256 + threadIdx.x;
    if (i >= NE) return;

    int src = esrc[i], dst = edst[i];
    float t = etim[i];

    const float4* qp = (const float4*)(qn + (size_t)dst * DD);
    const float4* kp = (const float4*)(kn + (size_t)src * DD);
    float qk0 = 0.f, qk1 = 0.f;
    #pragma unroll
    for (int c = 0; c < 16; c++) {
        float4 a = qp[c], b = kp[c];
        qk0 = fmaf(a.x, b.x, qk0); qk0 = fmaf(a.y, b.y, qk0);
        qk0 = fmaf(a.z, b.z, qk0); qk0 = fmaf(a.w, b.w, qk0);
    }
    #pragma unroll
    for (int c = 16; c < 32; c++) {
        float4 a = qp[c], b = kp[c];
        qk1 = fmaf(a.x, b.x, qk1); qk1 = fmaf(a.y, b.y, qk1);
        qk1 = fmaf(a.z, b.z, qk1); qk1 = fmaf(a.w, b.w, qk1);
    }

    const uint4* gp = (const uint4*)(G + (size_t)dst * 192);
    float u0 = 0.f, u1 = 0.f;

    // cos part: G[0..31] (h0) = gp[0..3], G[96..127] (h1) = gp[12..15]
    #pragma unroll
    for (int c = 0; c < 4; c++) {
        uint4 g0 = gp[c], g1 = gp[12 + c];
        float cj[8];
        #pragma unroll
        for (int j = 0; j < 8; j++)
            cj[j] = __cosf(fmaf(t, wt_s[8 * c + j], bt_s[8 * c + j]));
        float2 p;
        p = bf2x(g0.x); u0 = fmaf(cj[0], p.x, u0); u0 = fmaf(cj[1], p.y, u0);
        p = bf2x(g0.y); u0 = fmaf(cj[2], p.x, u0); u0 = fmaf(cj[3], p.y, u0);
        p = bf2x(g0.z); u0 = fmaf(cj[4], p.x, u0); u0 = fmaf(cj[5], p.y, u0);
        p = bf2x(g0.w); u0 = fmaf(cj[6], p.x, u0); u0 = fmaf(cj[7], p.y, u0);
        p = bf2x(g1.x); u1 = fmaf(cj[0], p.x, u1); u1 = fmaf(cj[1], p.y, u1);
        p = bf2x(g1.y); u1 = fmaf(cj[2], p.x, u1); u1 = fmaf(cj[3], p.y, u1);
        p = bf2x(g1.z); u1 = fmaf(cj[4], p.x, u1); u1 = fmaf(cj[5], p.y, u1);
        p = bf2x(g1.w); u1 = fmaf(cj[6], p.x, u1); u1 = fmaf(cj[7], p.y, u1);
    }

    // msg part: emsg row (bf16), G[32..95] = gp[4..11], G[128..191] = gp[16..23]
    const uint4* mp = (const uint4*)(emsg + ((size_t)i << 6));
    #pragma unroll
    for (int c = 0; c < 8; c++) {
        uint4 mu = mp[c];
        uint4 g0 = gp[4 + c], g1 = gp[16 + c];
        float2 m0 = bf2x(mu.x), m1 = bf2x(mu.y), m2 = bf2x(mu.z), m3 = bf2x(mu.w);
        float2 p;
        p = bf2x(g0.x); u0 = fmaf(m0.x, p.x, u0); u0 = fmaf(m0.y, p.y, u0);
        p = bf2x(g0.y); u0 = fmaf(m1.x, p.x, u0); u0 = fmaf(m1.y, p.y, u0);
        p = bf2x(g0.z); u0 = fmaf(m2.x, p.x, u0); u0 = fmaf(m2.y, p.y, u0);
        p = bf2x(g0.w); u0 = fmaf(m3.x, p.x, u0); u0 = fmaf(m3.y, p.y, u0);
        p = bf2x(g1.x); u1 = fmaf(m0.x, p.x, u1); u1 = fmaf(m0.y, p.y, u1);
        p = bf2x(g1.y); u1 = fmaf(m1.x, p.x, u1); u1 = fmaf(m1.y, p.y, u1);
        p = bf2x(g1.z); u1 = fmaf(m2.x, p.x, u1); u1 = fmaf(m2.y, p.y, u1);
        p = bf2x(g1.w); u1 = fmaf(m3.x, p.x, u1); u1 = fmaf(m3.y, p.y, u1);
    }

    float2 ex;
    ex.x = __expf((qk0 + u0) * 0.125f);
    ex.y = __expf((qk1 + u1) * 0.125f);
    exv[i] = ex;
}

// ---------------------------------------------------------------------------
// K2b: wave per dst node, pure streaming edge loop unrolled x4, no LDS.
// Writes outp = skip + acc/dn, plus S[n][192] and dn[n][2] for the epilogue.
// ---------------------------------------------------------------------------
__global__ __launch_bounds__(256) void agg_kernel(
    const int* __restrict__ esrc, const float* __restrict__ etim,
    const bf16* __restrict__ emsg,
    const float* __restrict__ Wt, const float* __restrict__ bt,
    const float* __restrict__ vn, const float2* __restrict__ exv,
    const int* __restrict__ seg,
    float* __restrict__ Sv, float* __restrict__ dnv,
    float* __restrict__ outp)
{
    __shared__ float wt_s[TDD], bt_s[TDD];
    if (threadIdx.x < TDD) {
        wt_s[threadIdx.x] = Wt[threadIdx.x];
        bt_s[threadIdx.x] = bt[threadIdx.x];
    }
    __syncthreads();

    const int lane = threadIdx.x & 63;
    const int gw = blockIdx.x * 4 + (threadIdx.x >> 6);
    const int NW = gridDim.x * 4;
    const bool half0 = (lane < 32);
    const float wtv = wt_s[lane & 31];
    const float btv = bt_s[lane & 31];
    const int mcol = half0 ? (32 + lane) : (lane - 32);

    for (int n = gw; n < NN; n += NW) {
        const int s0 = seg[n], s1 = seg[n + 1];

        float2 acc; acc.x = 0.f; acc.y = 0.f;
        float accd = 0.f;
        float s00 = 0.f, s01 = 0.f, s10 = 0.f, s11 = 0.f;

        int i = s0;
        #pragma unroll 1
        for (; i + 4 <= s1; i += 4) {
            int   srcu[4]; float2 exu[4]; float ttu[4]; float mgu[4]; float2 vvu[4];
            #pragma unroll
            for (int u = 0; u < 4; u++) {
                srcu[u] = esrc[i + u];
                exu[u]  = exv[i + u];
                ttu[u]  = etim[i + u];
                mgu[u]  = __bfloat162float(emsg[((size_t)(i + u) << 6) + mcol]);
            }
            #pragma unroll
            for (int u = 0; u < 4; u++)
                vvu[u] = *(const float2*)&vn[(size_t)srcu[u] * HCC + 2 * lane];
            #pragma unroll
            for (int u = 0; u < 4; u++) {
                float cs = __cosf(fmaf(ttu[u], wtv, btv));
                float r0 = half0 ? cs : mgu[u];
                float r1 = half0 ? mgu[u] : 0.f;
                float exh = half0 ? exu[u].x : exu[u].y;
                acc.x = fmaf(exh, vvu[u].x, acc.x);
                acc.y = fmaf(exh, vvu[u].y, acc.y);
                accd += exh;
                s00 = fmaf(exu[u].x, r0, s00); s01 = fmaf(exu[u].x, r1, s01);
                s10 = fmaf(exu[u].y, r0, s10); s11 = fmaf(exu[u].y, r1, s11);
            }
        }
        #pragma unroll 1
        for (; i < s1; i++) {
            int src = esrc[i];
            float2 ex = exv[i];
            float tt = etim[i];
            float mg = __bfloat162float(emsg[((size_t)i << 6) + mcol]);
            float2 v2 = *(const float2*)&vn[(size_t)src * HCC + 2 * lane];
            float cs = __cosf(fmaf(tt, wtv, btv));
            float r0 = half0 ? cs : mg;
            float r1 = half0 ? mg : 0.f;
            float exh = half0 ? ex.x : ex.y;
            acc.x = fmaf(exh, v2.x, acc.x);
            acc.y = fmaf(exh, v2.y, acc.y);
            accd += exh;
            s00 = fmaf(ex.x, r0, s00); s01 = fmaf(ex.x, r1, s01);
            s10 = fmaf(ex.y, r0, s10); s11 = fmaf(ex.y, r1, s11);
        }

        float dn = accd + 1e-16f;
        size_t sb = (size_t)n * 192;
        Sv[sb + lane]      = s00;
        Sv[sb + 96 + lane] = s10;
        if (half0) {
            Sv[sb + 64 + lane]  = s01;
            Sv[sb + 160 + lane] = s11;
        }
        if ((lane & 31) == 0) dnv[n * 2 + (lane >> 5)] = accd;

        size_t nb = (size_t)n * HCC + 2 * lane;
        float2 sk = *(const float2*)&outp[nb];   // skip from node_proj
        float2 o;
        o.x = acc.x / dn + sk.x;
        o.y = acc.y / dn + sk.y;
        *(float2*)&outp[nb] = o;
    }
}

// ---------------------------------------------------------------------------
// K3: epilogue GEMM, out += (S @ We)/dn. 32 nodes/block, S transposed in LDS.
// ---------------------------------------------------------------------------
__global__ __launch_bounds__(256) void epi_kernel(
    const float* __restrict__ Sv, const float* __restrict__ dnv,
    const float* __restrict__ We, float* __restrict__ outp)
{
    __shared__ float st[192 * 36];  // 27.6 KB, st[c*36 + node]
    const int node0 = blockIdx.x * 32;
    for (int idx = threadIdx.x; idx < 32 * 192; idx += 256) {
        int n = idx / 192, c = idx - n * 192;
        int node = node0 + n;
        st[c * 36 + n] = (node < NN) ? Sv[(size_t)node * 192 + c] : 0.f;
    }
    __syncthreads();

    const int wave = threadIdx.x >> 6;
    const int lane = threadIdx.x & 63;
    const int nb = wave * 8;
    const int hoff = (lane < 32) ? 0 : 96;
    const float2* We2 = (const float2*)We;

    float a[8][2];
    #pragma unroll
    for (int n = 0; n < 8; n++) { a[n][0] = 0.f; a[n][1] = 0.f; }

    #pragma unroll 8
    for (int j = 0; j < 96; j++) {
        float2 w = We2[j * 64 + lane];
        const float* sr = &st[(hoff + j) * 36 + nb];
        float sv[8];
        *(float4*)&sv[0] = *(const float4*)sr;
        *(float4*)&sv[4] = *(const float4*)(sr + 4);
        #pragma unroll
        for (int n = 0; n < 8; n++) {
            a[n][0] = fmaf(sv[n], w.x, a[n][0]);
            a[n][1] = fmaf(sv[n], w.y, a[n][1]);
        }
    }

    #pragma unroll 1
    for (int n = 0; n < 8; n++) {
        int node = node0 + nb + n;
        if (node >= NN) break;
        float dn = dnv[node * 2 + (lane >> 5)] + 1e-16f;
        size_t b = (size_t)node * HCC + 2 * lane;
        float2 o = *(const float2*)&outp[b];
        o.x += a[n][0] / dn;
        o.y += a[n][1] / dn;
        *(float2*)&outp[b] = o;
    }
}

extern "C" void kernel_launch(void* const* d_in, const int* in_sizes, int n_in,
                              void* d_out, int out_size, void* d_ws, size_t ws_size,
                              hipStream_t stream) {
    const float* x   = (const float*)d_in[0];
    const int* ei    = (const int*)d_in[1];
    const int* et    = (const int*)d_in[2];
    const float* msg = (const float*)d_in[3];
    const float* Wt  = (const float*)d_in[4];
    const float* bt  = (const float*)d_in[5];
    const float* Wq  = (const float*)d_in[6];
    const float* bq  = (const float*)d_in[7];
    const float* Wk  = (const float*)d_in[8];
    const float* bk  = (const float*)d_in[9];
    const float* Wv  = (const float*)d_in[10];
    const float* bv  = (const float*)d_in[11];
    const float* We  = (const float*)d_in[12];
    const float* Wsk = (const float*)d_in[13];
    const float* bsk = (const float*)d_in[14];

    const size_t nf = (size_t)NN * HCC;
    float* qn    = (float*)d_ws;
    float* kn    = qn + nf;
    float* vn    = kn + nf;
    bf16*  G     = (bf16*)(vn + nf);              // NN*192 bf16
    bf16*  emsg  = G + (size_t)NN * 192;          // NE*64 bf16
    float2* exv  = (float2*)(emsg + (size_t)NE * MDD);
    float* etim  = (float*)(exv + NE);
    float* Sv    = etim + NE;                     // NN*192 f32
    float* dnv   = Sv + (size_t)NN * 192;         // NN*2
    int* cnt     = (int*)(dnv + (size_t)NN * 2);
    int* seg     = cnt + NN;                      // NN+1
    int* cur     = seg + NN + 1;
    int* perm    = cur + NN;
    int* esrc    = perm + NE;
    int* edst    = esrc + NE;
    int* bsum    = edst + NE;
    int* boff    = bsum + 256;
    size_t need  = (size_t)((char*)(boff + 256) - (char*)d_ws);
    if (ws_size < need) return;

    float* outp = (float*)d_out;

    node_proj_kernel<<<(NN + 63) / 64, 256, 0, stream>>>(
        x, Wq, bq, Wk, bk, Wv, bv, Wsk, bsk, qn, kn, vn, outp, cnt);
    g_kernel<<<(NN + 31) / 32, 256, 0, stream>>>(qn, We, G);
    hist_kernel<<<(NE + 255) / 256, 256, 0, stream>>>(ei, cnt);
    scan_a_kernel<<<196, 256, 0, stream>>>(cnt, bsum);
    scan_b_kernel<<<1, 256, 0, stream>>>(bsum, boff, seg);
    scan_c_kernel<<<196, 256, 0, stream>>>(cnt, boff, seg, cur);
    scatter_kernel<<<(NE + 255) / 256, 256, 0, stream>>>(
        ei, et, cur, perm, esrc, edst, etim);
    msg_gather_kernel<<<(int)(((size_t)NE * MDD + 255) / 256), 256, 0, stream>>>(
        msg, perm, emsg);
    score_kernel<<<(NE + 255) / 256, 256, 0, stream>>>(
        esrc, edst, etim, emsg, Wt, bt, qn, kn, G, exv);
    agg_kernel<<<3125, 256, 0, stream>>>(
        esrc, etim, emsg, Wt, bt, vn, exv, seg, Sv, dnv, outp);
    epi_kernel<<<(NN + 31) / 32, 256, 0, stream>>>(Sv, dnv, We, outp);
}

// Round 6
// 677.300 us; speedup vs baseline: 4.0246x; 1.2001x over previous
//
#include <hip/hip_runtime.h>
#include <hip/hip_bf16.h>

#define NN 50000
#define NE 500000
#define DD 128
#define HCC 128
#define TDD 32
#define MDD 64

typedef __hip_bfloat16 bf16;
typedef _Float16 f16;
typedef __attribute__((ext_vector_type(8))) _Float16 f16x8;
typedef __attribute__((ext_vector_type(2))) _Float16 f16x2;
typedef __attribute__((ext_vector_type(4))) float f32x4;

__device__ __forceinline__ float2 bf2x(unsigned u) {
    union { unsigned v; float f; } a, b;
    a.v = u << 16; b.v = u & 0xffff0000u;
    float2 r; r.x = a.f; r.y = b.f; return r;
}

// ---------------------------------------------------------------------------
// conv_x: x (f32) -> xh (f16)
// ---------------------------------------------------------------------------
__global__ __launch_bounds__(256) void conv_x_kernel(
    const float* __restrict__ x, f16* __restrict__ xh)
{
    int i = blockIdx.x * 256 + threadIdx.x;          // float4 index
    if (i >= NN * DD / 4) return;
    float4 v = ((const float4*)x)[i];
    f16 o[4] = { (f16)v.x, (f16)v.y, (f16)v.z, (f16)v.w };
    *(uint2*)&xh[(size_t)i * 4] = *(uint2*)o;
}

// ---------------------------------------------------------------------------
// conv_w: WTh[n][k] = Wcat[k][n] (f16, n in [0,512): q|k|v|skip), Weh = We f16,
// and zero cnt.
// ---------------------------------------------------------------------------
__global__ __launch_bounds__(256) void conv_w_kernel(
    const float* __restrict__ Wq, const float* __restrict__ Wk,
    const float* __restrict__ Wv, const float* __restrict__ Wsk,
    const float* __restrict__ We,
    f16* __restrict__ WTh, f16* __restrict__ Weh, int* __restrict__ cnt)
{
    int idx = blockIdx.x * 256 + threadIdx.x;
    if (idx < 512 * 128) {
        int n = idx >> 7, k = idx & 127;
        int mat = n >> 7, col = n & 127;
        const float* W = (mat == 0) ? Wq : (mat == 1) ? Wk : (mat == 2) ? Wv : Wsk;
        WTh[idx] = (f16)W[k * 128 + col];
    } else if (idx < 512 * 128 + 96 * 128) {
        int i = idx - 512 * 128;
        Weh[i] = (f16)We[i];
    } else if (idx < 512 * 128 + 96 * 128 + NN) {
        cnt[idx - (512 * 128 + 96 * 128)] = 0;
    }
}

// ---------------------------------------------------------------------------
// K1 (MFMA): out[g] = x @ W[g] + b[g].  grid = (782, 4).
// Block: 64 nodes x 128 cols. Wave: 16 nodes x 128 cols (8 col-tiles, K=128).
// g<3 -> f16 outputs (qh/kh/vh); g==3 -> f32 skip written to outp.
// LDS rows padded to 136 f16 (272 B): 2-way bank alias (free), 16B aligned.
// ---------------------------------------------------------------------------
__global__ __launch_bounds__(256) void node_proj_kernel(
    const f16* __restrict__ xh, const f16* __restrict__ WTh,
    const float* __restrict__ bq, const float* __restrict__ bk,
    const float* __restrict__ bv, const float* __restrict__ bsk,
    f16* __restrict__ qh, f16* __restrict__ kh, f16* __restrict__ vh,
    float* __restrict__ outp)
{
    __shared__ f16 xs[64 * 136];    // 17408 B
    __shared__ f16 ws[128 * 136];   // 34816 B

    const int node0 = blockIdx.x * 64;
    const int g = blockIdx.y;

    // stage x tile (64 x 128), 4 f16 per thread-iter
    for (int i = threadIdx.x; i < 64 * 32; i += 256) {
        int node = i >> 5, koff = (i & 31) * 4;
        int gn = node0 + node;
        uint2 val = {0u, 0u};
        if (gn < NN) val = *(const uint2*)&xh[(size_t)gn * DD + koff];
        *(uint2*)&xs[node * 136 + koff] = val;
    }
    // stage W^T tile (128 cols x 128 k) for matrix g
    const f16* wt = WTh + (size_t)g * 128 * 128;
    for (int i = threadIdx.x; i < 128 * 32; i += 256) {
        int n = i >> 5, koff = (i & 31) * 4;
        *(uint2*)&ws[n * 136 + koff] = *(const uint2*)&wt[n * 128 + koff];
    }
    __syncthreads();

    const int wave = threadIdx.x >> 6;
    const int lane = threadIdx.x & 63;
    const int m0 = wave * 16;
    const int lrow = lane & 15;          // A/B row-or-col index
    const int lk = (lane >> 4) * 8;      // k-chunk offset within 32

    f32x4 acc[8];
    #pragma unroll
    for (int t = 0; t < 8; t++) acc[t] = (f32x4){0.f, 0.f, 0.f, 0.f};

    #pragma unroll
    for (int kc = 0; kc < 4; kc++) {
        f16x8 a = *(const f16x8*)&xs[(m0 + lrow) * 136 + kc * 32 + lk];
        #pragma unroll
        for (int t = 0; t < 8; t++) {
            f16x8 b = *(const f16x8*)&ws[(t * 16 + lrow) * 136 + kc * 32 + lk];
            acc[t] = __builtin_amdgcn_mfma_f32_16x16x32_f16(a, b, acc[t], 0, 0, 0);
        }
    }

    const float* bias = (g == 0) ? bq : (g == 1) ? bk : (g == 2) ? bv : bsk;
    f16* outh = (g == 0) ? qh : (g == 1) ? kh : vh;

    #pragma unroll 1
    for (int t = 0; t < 8; t++) {
        int col = t * 16 + lrow;
        float bc = bias[col];
        #pragma unroll
        for (int r = 0; r < 4; r++) {
            int node = node0 + m0 + (lane >> 4) * 4 + r;
            if (node < NN) {
                float val = acc[t][r] + bc;
                if (g < 3) outh[(size_t)node * HCC + col] = (f16)val;
                else       outp[(size_t)node * HCC + col] = val;
            }
        }
    }
}

// ---------------------------------------------------------------------------
// K1b (MFMA): G[n][h*96+j] = sum_c qh[n][h*64+c] * Weh[j][h*64+c]  (bf16 out)
// Block: 64 nodes x 192 cols; wave: 16 nodes, 12 col-tiles (h = t/6), K=64.
// ---------------------------------------------------------------------------
__global__ __launch_bounds__(256) void g_kernel(
    const f16* __restrict__ qh, const f16* __restrict__ Weh,
    bf16* __restrict__ G)
{
    __shared__ f16 qs[64 * 136];   // 17408 B
    __shared__ f16 ws[96 * 136];   // 26112 B

    const int node0 = blockIdx.x * 64;
    for (int i = threadIdx.x; i < 64 * 32; i += 256) {
        int node = i >> 5, koff = (i & 31) * 4;
        int gn = node0 + node;
        uint2 val = {0u, 0u};
        if (gn < NN) val = *(const uint2*)&qh[(size_t)gn * DD + koff];
        *(uint2*)&qs[node * 136 + koff] = val;
    }
    for (int i = threadIdx.x; i < 96 * 32; i += 256) {
        int j = i >> 5, koff = (i & 31) * 4;
        *(uint2*)&ws[j * 136 + koff] = *(const uint2*)&Weh[j * 128 + koff];
    }
    __syncthreads();

    const int wave = threadIdx.x >> 6;
    const int lane = threadIdx.x & 63;
    const int m0 = wave * 16;
    const int lrow = lane & 15;
    const int lk = (lane >> 4) * 8;

    // preload the 4 A-fragments: (h, kc) in {0,1} x {0,1}
    f16x8 afr[4];
    #pragma unroll
    for (int hk = 0; hk < 4; hk++) {
        int h = hk >> 1, kc = hk & 1;
        afr[hk] = *(const f16x8*)&qs[(m0 + lrow) * 136 + h * 64 + kc * 32 + lk];
    }

    f32x4 acc[12];
    #pragma unroll
    for (int t = 0; t < 12; t++) acc[t] = (f32x4){0.f, 0.f, 0.f, 0.f};

    #pragma unroll
    for (int t = 0; t < 12; t++) {
        int h = (t < 6) ? 0 : 1;
        int jt = (t < 6) ? t : t - 6;
        #pragma unroll
        for (int kc = 0; kc < 2; kc++) {
            f16x8 b = *(const f16x8*)&ws[(jt * 16 + lrow) * 136 + h * 64 + kc * 32 + lk];
            acc[t] = __builtin_amdgcn_mfma_f32_16x16x32_f16(afr[h * 2 + kc], b, acc[t], 0, 0, 0);
        }
    }

    #pragma unroll 1
    for (int t = 0; t < 12; t++) {
        int h = (t < 6) ? 0 : 1;
        int jt = (t < 6) ? t : t - 6;
        int col = h * 96 + jt * 16 + lrow;
        #pragma unroll
        for (int r = 0; r < 4; r++) {
            int node = node0 + m0 + (lane >> 4) * 4 + r;
            if (node < NN) G[(size_t)node * 192 + col] = __float2bfloat16(acc[t][r]);
        }
    }
}

// --------------------------- sort pipeline ----------------------------------
__global__ __launch_bounds__(256) void hist_kernel(
    const int* __restrict__ ei, int* __restrict__ cnt)
{
    int gid = blockIdx.x * 256 + threadIdx.x;
    if (gid < NE) atomicAdd(&cnt[ei[NE + gid]], 1);
}

__global__ __launch_bounds__(256) void scan_a_kernel(
    const int* __restrict__ cnt, int* __restrict__ bsum)
{
    __shared__ int red[256];
    int gid = blockIdx.x * 256 + threadIdx.x;
    red[threadIdx.x] = (gid < NN) ? cnt[gid] : 0;
    __syncthreads();
    for (int off = 128; off > 0; off >>= 1) {
        if (threadIdx.x < off) red[threadIdx.x] += red[threadIdx.x + off];
        __syncthreads();
    }
    if (threadIdx.x == 0) bsum[blockIdx.x] = red[0];
}

__global__ __launch_bounds__(256) void scan_b_kernel(
    const int* __restrict__ bsum, int* __restrict__ boff, int* __restrict__ seg)
{
    __shared__ int s[256];
    int t = threadIdx.x;
    s[t] = (t < 196) ? bsum[t] : 0;
    __syncthreads();
    if (t == 0) {
        int run = 0;
        for (int b = 0; b < 196; b++) { int v = s[b]; s[b] = run; run += v; }
        seg[NN] = NE;
    }
    __syncthreads();
    if (t < 196) boff[t] = s[t];
}

__global__ __launch_bounds__(256) void scan_c_kernel(
    const int* __restrict__ cnt, const int* __restrict__ boff,
    int* __restrict__ seg, int* __restrict__ cur)
{
    __shared__ int s[256];
    int gid = blockIdx.x * 256 + threadIdx.x;
    int v = (gid < NN) ? cnt[gid] : 0;
    s[threadIdx.x] = v;
    __syncthreads();
    for (int off = 1; off < 256; off <<= 1) {
        int t = (threadIdx.x >= off) ? s[threadIdx.x - off] : 0;
        __syncthreads();
        s[threadIdx.x] += t;
        __syncthreads();
    }
    int excl = s[threadIdx.x] - v + boff[blockIdx.x];
    if (gid < NN) { seg[gid] = excl; cur[gid] = excl; }
}

__global__ __launch_bounds__(256) void scatter_kernel(
    const int* __restrict__ ei, const int* __restrict__ et,
    int* __restrict__ cur, int* __restrict__ perm,
    int* __restrict__ esrc, int* __restrict__ edst, float* __restrict__ etim)
{
    int gid = blockIdx.x * 256 + threadIdx.x;
    if (gid < NE) {
        int d = ei[NE + gid];
        int pos = atomicAdd(&cur[d], 1);
        perm[pos] = gid;
        esrc[pos] = ei[gid];
        edst[pos] = d;
        etim[pos] = (float)et[gid];
    }
}

__global__ __launch_bounds__(256) void msg_gather_kernel(
    const float* __restrict__ msg, const int* __restrict__ perm,
    bf16* __restrict__ emsg)
{
    size_t idx = (size_t)blockIdx.x * 256 + threadIdx.x;
    if (idx >= (size_t)NE * MDD) return;
    int i = (int)(idx >> 6);
    int c = (int)(idx & 63);
    emsg[idx] = __float2bfloat16(msg[((size_t)perm[i] << 6) + c]);
}

// ---------------------------------------------------------------------------
// K2a: one THREAD per sorted edge (f16 q/k, dot2 HW path where available).
// ---------------------------------------------------------------------------
__global__ __launch_bounds__(256) void score_kernel(
    const int* __restrict__ esrc, const int* __restrict__ edst,
    const float* __restrict__ etim,
    const bf16* __restrict__ emsg,
    const float* __restrict__ Wt, const float* __restrict__ bt,
    const f16* __restrict__ qh, const f16* __restrict__ kh,
    const bf16* __restrict__ G, float2* __restrict__ exv)
{
    __shared__ float wt_s[TDD], bt_s[TDD];
    if (threadIdx.x < TDD) {
        wt_s[threadIdx.x] = Wt[threadIdx.x];
        bt_s[threadIdx.x] = bt[threadIdx.x];
    }
    __syncthreads();

    int i = blockIdx.x * 256 + threadIdx.x;
    if (i >= NE) return;

    int src = esrc[i], dst = edst[i];
    float t = etim[i];

    union U16 { uint4 u; f16x2 h[4]; };
    const uint4* qp = (const uint4*)(qh + (size_t)dst * DD);  // 8 f16 each
    const uint4* kp = (const uint4*)(kh + (size_t)src * DD);
    float qk0 = 0.f, qk1 = 0.f;
    #pragma unroll
    for (int c = 0; c < 8; c++) {
        U16 a, b; a.u = qp[c]; b.u = kp[c];
        #pragma unroll
        for (int j = 0; j < 4; j++) {
#if defined(__has_builtin) && __has_builtin(__builtin_amdgcn_fdot2)
            qk0 = __builtin_amdgcn_fdot2(a.h[j], b.h[j], qk0, false);
#else
            qk0 = fmaf((float)a.h[j][0], (float)b.h[j][0], qk0);
            qk0 = fmaf((float)a.h[j][1], (float)b.h[j][1], qk0);
#endif
        }
    }
    #pragma unroll
    for (int c = 8; c < 16; c++) {
        U16 a, b; a.u = qp[c]; b.u = kp[c];
        #pragma unroll
        for (int j = 0; j < 4; j++) {
#if defined(__has_builtin) && __has_builtin(__builtin_amdgcn_fdot2)
            qk1 = __builtin_amdgcn_fdot2(a.h[j], b.h[j], qk1, false);
#else
            qk1 = fmaf((float)a.h[j][0], (float)b.h[j][0], qk1);
            qk1 = fmaf((float)a.h[j][1], (float)b.h[j][1], qk1);
#endif
        }
    }

    const uint4* gp = (const uint4*)(G + (size_t)dst * 192);
    float u0 = 0.f, u1 = 0.f;

    // cos part: G[0..31] (h0) = gp[0..3], G[96..127] (h1) = gp[12..15]
    #pragma unroll
    for (int c = 0; c < 4; c++) {
        uint4 g0 = gp[c], g1 = gp[12 + c];
        float cj[8];
        #pragma unroll
        for (int j = 0; j < 8; j++)
            cj[j] = __cosf(fmaf(t, wt_s[8 * c + j], bt_s[8 * c + j]));
        float2 p;
        p = bf2x(g0.x); u0 = fmaf(cj[0], p.x, u0); u0 = fmaf(cj[1], p.y, u0);
        p = bf2x(g0.y); u0 = fmaf(cj[2], p.x, u0); u0 = fmaf(cj[3], p.y, u0);
        p = bf2x(g0.z); u0 = fmaf(cj[4], p.x, u0); u0 = fmaf(cj[5], p.y, u0);
        p = bf2x(g0.w); u0 = fmaf(cj[6], p.x, u0); u0 = fmaf(cj[7], p.y, u0);
        p = bf2x(g1.x); u1 = fmaf(cj[0], p.x, u1); u1 = fmaf(cj[1], p.y, u1);
        p = bf2x(g1.y); u1 = fmaf(cj[2], p.x, u1); u1 = fmaf(cj[3], p.y, u1);
        p = bf2x(g1.z); u1 = fmaf(cj[4], p.x, u1); u1 = fmaf(cj[5], p.y, u1);
        p = bf2x(g1.w); u1 = fmaf(cj[6], p.x, u1); u1 = fmaf(cj[7], p.y, u1);
    }

    // msg part
    const uint4* mp = (const uint4*)(emsg + ((size_t)i << 6));
    #pragma unroll
    for (int c = 0; c < 8; c++) {
        uint4 mu = mp[c];
        uint4 g0 = gp[4 + c], g1 = gp[16 + c];
        float2 m0 = bf2x(mu.x), m1 = bf2x(mu.y), m2 = bf2x(mu.z), m3 = bf2x(mu.w);
        float2 p;
        p = bf2x(g0.x); u0 = fmaf(m0.x, p.x, u0); u0 = fmaf(m0.y, p.y, u0);
        p = bf2x(g0.y); u0 = fmaf(m1.x, p.x, u0); u0 = fmaf(m1.y, p.y, u0);
        p = bf2x(g0.z); u0 = fmaf(m2.x, p.x, u0); u0 = fmaf(m2.y, p.y, u0);
        p = bf2x(g0.w); u0 = fmaf(m3.x, p.x, u0); u0 = fmaf(m3.y, p.y, u0);
        p = bf2x(g1.x); u1 = fmaf(m0.x, p.x, u1); u1 = fmaf(m0.y, p.y, u1);
        p = bf2x(g1.y); u1 = fmaf(m1.x, p.x, u1); u1 = fmaf(m1.y, p.y, u1);
        p = bf2x(g1.z); u1 = fmaf(m2.x, p.x, u1); u1 = fmaf(m2.y, p.y, u1);
        p = bf2x(g1.w); u1 = fmaf(m3.x, p.x, u1); u1 = fmaf(m3.y, p.y, u1);
    }

    float2 ex;
    ex.x = __expf((qk0 + u0) * 0.125f);
    ex.y = __expf((qk1 + u1) * 0.125f);
    exv[i] = ex;
}

// ---------------------------------------------------------------------------
// K2b: wave per dst node, streaming edge loop x4, f16 v gathers.
// ---------------------------------------------------------------------------
__global__ __launch_bounds__(256) void agg_kernel(
    const int* __restrict__ esrc, const float* __restrict__ etim,
    const bf16* __restrict__ emsg,
    const float* __restrict__ Wt, const float* __restrict__ bt,
    const f16* __restrict__ vh, const float2* __restrict__ exv,
    const int* __restrict__ seg,
    float* __restrict__ Sv, float* __restrict__ dnv,
    float* __restrict__ outp)
{
    __shared__ float wt_s[TDD], bt_s[TDD];
    if (threadIdx.x < TDD) {
        wt_s[threadIdx.x] = Wt[threadIdx.x];
        bt_s[threadIdx.x] = bt[threadIdx.x];
    }
    __syncthreads();

    const int lane = threadIdx.x & 63;
    const int gw = blockIdx.x * 4 + (threadIdx.x >> 6);
    const int NW = gridDim.x * 4;
    const bool half0 = (lane < 32);
    const float wtv = wt_s[lane & 31];
    const float btv = bt_s[lane & 31];
    const int mcol = half0 ? (32 + lane) : (lane - 32);

    for (int n = gw; n < NN; n += NW) {
        const int s0 = seg[n], s1 = seg[n + 1];

        float2 acc; acc.x = 0.f; acc.y = 0.f;
        float accd = 0.f;
        float s00 = 0.f, s01 = 0.f, s10 = 0.f, s11 = 0.f;

        int i = s0;
        #pragma unroll 1
        for (; i + 4 <= s1; i += 4) {
            int srcu[4]; float2 exu[4]; float ttu[4]; float mgu[4]; f16x2 vvu[4];
            #pragma unroll
            for (int u = 0; u < 4; u++) {
                srcu[u] = esrc[i + u];
                exu[u]  = exv[i + u];
                ttu[u]  = etim[i + u];
                mgu[u]  = __bfloat162float(emsg[((size_t)(i + u) << 6) + mcol]);
            }
            #pragma unroll
            for (int u = 0; u < 4; u++)
                vvu[u] = *(const f16x2*)&vh[(size_t)srcu[u] * HCC + 2 * lane];
            #pragma unroll
            for (int u = 0; u < 4; u++) {
                float cs = __cosf(fmaf(ttu[u], wtv, btv));
                float r0 = half0 ? cs : mgu[u];
                float r1 = half0 ? mgu[u] : 0.f;
                float exh = half0 ? exu[u].x : exu[u].y;
                acc.x = fmaf(exh, (float)vvu[u][0], acc.x);
                acc.y = fmaf(exh, (float)vvu[u][1], acc.y);
                accd += exh;
                s00 = fmaf(exu[u].x, r0, s00); s01 = fmaf(exu[u].x, r1, s01);
                s10 = fmaf(exu[u].y, r0, s10); s11 = fmaf(exu[u].y, r1, s11);
            }
        }
        #pragma unroll 1
        for (; i < s1; i++) {
            int src = esrc[i];
            float2 ex = exv[i];
            float tt = etim[i];
            float mg = __bfloat162float(emsg[((size_t)i << 6) + mcol]);
            f16x2 v2 = *(const f16x2*)&vh[(size_t)src * HCC + 2 * lane];
            float cs = __cosf(fmaf(tt, wtv, btv));
            float r0 = half0 ? cs : mg;
            float r1 = half0 ? mg : 0.f;
            float exh = half0 ? ex.x : ex.y;
            acc.x = fmaf(exh, (float)v2[0], acc.x);
            acc.y = fmaf(exh, (float)v2[1], acc.y);
            accd += exh;
            s00 = fmaf(ex.x, r0, s00); s01 = fmaf(ex.x, r1, s01);
            s10 = fmaf(ex.y, r0, s10); s11 = fmaf(ex.y, r1, s11);
        }

        float dn = accd + 1e-16f;
        size_t sb = (size_t)n * 192;
        Sv[sb + lane]      = s00;
        Sv[sb + 96 + lane] = s10;
        if (half0) {
            Sv[sb + 64 + lane]  = s01;
            Sv[sb + 160 + lane] = s11;
        }
        if ((lane & 31) == 0) dnv[n * 2 + (lane >> 5)] = accd;

        size_t nb = (size_t)n * HCC + 2 * lane;
        float2 sk = *(const float2*)&outp[nb];   // skip from node_proj
        float2 o;
        o.x = acc.x / dn + sk.x;
        o.y = acc.y / dn + sk.y;
        *(float2*)&outp[nb] = o;
    }
}

// ---------------------------------------------------------------------------
// K3: epilogue GEMM, out += (S @ We)/dn. 32 nodes/block, S transposed in LDS.
// ---------------------------------------------------------------------------
__global__ __launch_bounds__(256) void epi_kernel(
    const float* __restrict__ Sv, const float* __restrict__ dnv,
    const float* __restrict__ We, float* __restrict__ outp)
{
    __shared__ float st[192 * 36];  // 27.6 KB, st[c*36 + node]
    const int node0 = blockIdx.x * 32;
    for (int idx = threadIdx.x; idx < 32 * 192; idx += 256) {
        int n = idx / 192, c = idx - n * 192;
        int node = node0 + n;
        st[c * 36 + n] = (node < NN) ? Sv[(size_t)node * 192 + c] : 0.f;
    }
    __syncthreads();

    const int wave = threadIdx.x >> 6;
    const int lane = threadIdx.x & 63;
    const int nb = wave * 8;
    const int hoff = (lane < 32) ? 0 : 96;
    const float2* We2 = (const float2*)We;

    float a[8][2];
    #pragma unroll
    for (int n = 0; n < 8; n++) { a[n][0] = 0.f; a[n][1] = 0.f; }

    #pragma unroll 8
    for (int j = 0; j < 96; j++) {
        float2 w = We2[j * 64 + lane];
        const float* sr = &st[(hoff + j) * 36 + nb];
        float sv[8];
        *(float4*)&sv[0] = *(const float4*)sr;
        *(float4*)&sv[4] = *(const float4*)(sr + 4);
        #pragma unroll
        for (int n = 0; n < 8; n++) {
            a[n][0] = fmaf(sv[n], w.x, a[n][0]);
            a[n][1] = fmaf(sv[n], w.y, a[n][1]);
        }
    }

    #pragma unroll 1
    for (int n = 0; n < 8; n++) {
        int node = node0 + nb + n;
        if (node >= NN) break;
        float dn = dnv[node * 2 + (lane >> 5)] + 1e-16f;
        size_t b = (size_t)node * HCC + 2 * lane;
        float2 o = *(const float2*)&outp[b];
        o.x += a[n][0] / dn;
        o.y += a[n][1] / dn;
        *(float2*)&outp[b] = o;
    }
}

extern "C" void kernel_launch(void* const* d_in, const int* in_sizes, int n_in,
                              void* d_out, int out_size, void* d_ws, size_t ws_size,
                              hipStream_t stream) {
    const float* x   = (const float*)d_in[0];
    const int* ei    = (const int*)d_in[1];
    const int* et    = (const int*)d_in[2];
    const float* msg = (const float*)d_in[3];
    const float* Wt  = (const float*)d_in[4];
    const float* bt  = (const float*)d_in[5];
    const float* Wq  = (const float*)d_in[6];
    const float* bq  = (const float*)d_in[7];
    const float* Wk  = (const float*)d_in[8];
    const float* bk  = (const float*)d_in[9];
    const float* Wv  = (const float*)d_in[10];
    const float* bv  = (const float*)d_in[11];
    const float* We  = (const float*)d_in[12];
    const float* Wsk = (const float*)d_in[13];
    const float* bsk = (const float*)d_in[14];

    const size_t nf = (size_t)NN * HCC;
    f16* xh      = (f16*)d_ws;                    // NN*128
    f16* qh      = xh + nf;
    f16* kh      = qh + nf;
    f16* vh      = kh + nf;
    f16* WTh     = vh + nf;                       // 512*128
    f16* Weh     = WTh + 512 * 128;               // 96*128
    bf16* G      = (bf16*)(Weh + 96 * 128);       // NN*192
    bf16* emsg   = G + (size_t)NN * 192;          // NE*64
    float2* exv  = (float2*)(emsg + (size_t)NE * MDD);
    float* etim  = (float*)(exv + NE);
    float* Sv    = etim + NE;                     // NN*192
    float* dnv   = Sv + (size_t)NN * 192;         // NN*2
    int* cnt     = (int*)(dnv + (size_t)NN * 2);
    int* seg     = cnt + NN;                      // NN+1
    int* cur     = seg + NN + 1;
    int* perm    = cur + NN;
    int* esrc    = perm + NE;
    int* edst    = esrc + NE;
    int* bsum    = edst + NE;
    int* boff    = bsum + 256;
    size_t need  = (size_t)((char*)(boff + 256) - (char*)d_ws);
    if (ws_size < need) return;

    float* outp = (float*)d_out;

    conv_x_kernel<<<(NN * DD / 4 + 255) / 256, 256, 0, stream>>>(x, xh);
    conv_w_kernel<<<(512 * 128 + 96 * 128 + NN + 255) / 256, 256, 0, stream>>>(
        Wq, Wk, Wv, Wsk, We, WTh, Weh, cnt);
    dim3 npgrid((NN + 63) / 64, 4);
    node_proj_kernel<<<npgrid, 256, 0, stream>>>(
        xh, WTh, bq, bk, bv, bsk, qh, kh, vh, outp);
    g_kernel<<<(NN + 63) / 64, 256, 0, stream>>>(qh, Weh, G);
    hist_kernel<<<(NE + 255) / 256, 256, 0, stream>>>(ei, cnt);
    scan_a_kernel<<<196, 256, 0, stream>>>(cnt, bsum);
    scan_b_kernel<<<1, 256, 0, stream>>>(bsum, boff, seg);
    scan_c_kernel<<<196, 256, 0, stream>>>(cnt, boff, seg, cur);
    scatter_kernel<<<(NE + 255) / 256, 256, 0, stream>>>(
        ei, et, cur, perm, esrc, edst, etim);
    msg_gather_kernel<<<(int)(((size_t)NE * MDD + 255) / 256), 256, 0, stream>>>(
        msg, perm, emsg);
    score_kernel<<<(NE + 255) / 256, 256, 0, stream>>>(
        esrc, edst, etim, emsg, Wt, bt, qh, kh, G, exv);
    agg_kernel<<<3125, 256, 0, stream>>>(
        esrc, etim, emsg, Wt, bt, vh, exv, seg, Sv, dnv, outp);
    epi_kernel<<<(NN + 31) / 32, 256, 0, stream>>>(Sv, dnv, We, outp);
}